// Round 6
// baseline (476.608 us; speedup 1.0000x reference)
//
#include <hip/hip_runtime.h>
#include <hip/hip_bf16.h>
#include <hip/hip_cooperative_groups.h>

namespace cg = cooperative_groups;

using sh8   = __attribute__((ext_vector_type(8))) short;
using f32x4 = __attribute__((ext_vector_type(4))) float;

#define DEV __device__ __forceinline__

DEV float leaky(float x) { return x >= 0.f ? x : 0.2f * x; }

DEV unsigned short f2bf(float f) {  // round-to-nearest-even f32 -> bf16 bits
  unsigned u = __float_as_uint(f);
  u += 0x7FFF + ((u >> 16) & 1);
  return (unsigned short)(u >> 16);
}
DEV float bf2f(unsigned short b) { return __uint_as_float(((unsigned)b) << 16); }

// ---------------- weight pack: f32 [Cout][Cin][7] -> bf16 [7][Cin/32][Cout][32] ----------------
DEV void pack_one(const float* __restrict__ w, unsigned short* __restrict__ wp,
                  int Cout, int Cin, int tid, int nthr) {
  int n = Cout * Cin * 7;
  int nCib = Cin >> 5;
  for (int i = tid; i < n; i += nthr) {
    int co = i / (Cin * 7);
    int r  = i - co * (Cin * 7);
    int ci = r / 7;
    int k  = r - ci * 7;
    wp[((long)(k * nCib + (ci >> 5)) * Cout + co) * 32 + (ci & 31)] = f2bf(w[i]);
  }
}

// ---------------- embed (MFMA GEMM) + fused ctx + fused weight packing ----------------
// blocks [0,512): embed one (b,band) group of 128 rows. blocks [512,1024): pack conv weights.
__global__ __launch_bounds__(256)
void embed_mfma(const float* __restrict__ x, const float* __restrict__ ew,
                const float* __restrict__ eb, unsigned short* __restrict__ encbf,
                float* __restrict__ ctx,
                const float* __restrict__ cw1, const float* __restrict__ cw2,
                const float* __restrict__ cw3, const float* __restrict__ cw4,
                unsigned short* __restrict__ wbuf) {
  if (blockIdx.x >= 512) {
    int tid = (blockIdx.x - 512) * 256 + threadIdx.x;
    int nthr = 512 * 256;
    pack_one(cw1, wbuf,           512, 1024, tid, nthr);
    pack_one(cw2, wbuf + 3670016, 256,  512, tid, nthr);
    pack_one(cw3, wbuf + 4587520, 128,  256, tid, nthr);
    pack_one(cw4, wbuf + 4816896,  64,  128, tid, nthr);
    return;
  }
  __shared__ unsigned short W16[257 * 16];   // [p][f], f>=8 zeroed
  __shared__ float ctxred[4][8];
  const int tid = threadIdx.x;

  for (int i = tid; i < 257 * 16; i += 256) {
    int p = i >> 4, f = i & 15;
    W16[i] = (f < 8) ? f2bf(ew[p * 8 + f]) : (unsigned short)0;
  }
  __syncthreads();

  const int w = tid >> 6, lane = tid & 63;
  const int m = lane & 15, g = lane >> 4;

  sh8 breg[8];
  #pragma unroll
  for (int kk = 0; kk < 8; ++kk) {
    #pragma unroll
    for (int j = 0; j < 8; ++j)
      breg[kk][j] = (short)W16[(kk * 32 + g * 8 + j) * 16 + m];
  }
  const float w256 = bf2f(W16[256 * 16 + m]);
  const float ebf = (m < 8) ? eb[m] : 0.f;

  const int bid = blockIdx.x;               // 512 groups
  const long rowbase = (long)bid * 128;
  const int b = bid >> 7, band = bid & 127;

  float ctx_acc = 0.f;
  #pragma unroll
  for (int s = 0; s < 2; ++s) {
    const int t0 = w * 32 + s * 16;
    const float* xp = x + (rowbase + t0 + m) * 257;
    f32x4 acc = {0.f, 0.f, 0.f, 0.f};
    #pragma unroll
    for (int kk = 0; kk < 8; ++kk) {
      const float* xk = xp + kk * 32 + g * 8;
      sh8 afr;
      #pragma unroll
      for (int j = 0; j < 8; ++j) afr[j] = (short)f2bf(xk[j]);
      acc = __builtin_amdgcn_mfma_f32_16x16x32_bf16(afr, breg[kk], acc, 0, 0, 0);
    }
    const float* xq = x + (rowbase + t0 + g * 4) * 257 + 256;
    unsigned short pk[4];
    #pragma unroll
    for (int r = 0; r < 4; ++r) {
      float e = acc[r] + xq[(long)r * 257] * w256 + ebf;
      pk[r] = f2bf(e);
      ctx_acc += e;
    }
    if (m < 8) {
      long o = ((long)b * 1024 + m * 128 + band) * 128 + t0 + g * 4;
      *(ushort4*)(encbf + o) = make_ushort4(pk[0], pk[1], pk[2], pk[3]);
    }
  }
  ctx_acc += __shfl_xor(ctx_acc, 16);
  ctx_acc += __shfl_xor(ctx_acc, 32);
  if (lane < 8) ctxred[w][lane] = ctx_acc;
  __syncthreads();
  if (tid < 8) {
    float sv = ctxred[0][tid] + ctxred[1][tid] + ctxred[2][tid] + ctxred[3][tid];
    ctx[(long)b * 1024 + tid * 128 + band] = sv;
  }
}

// ---------------- cooperative MLP: 3 GEMMs + 2 LN + fin, one kernel ----------------
DEV void gemm_core(float hl[4][128], float red[8][4][32],
                   const float* __restrict__ w, float* __restrict__ dst,
                   int jb, int kc, int k0) {
  const int jl = threadIdx.x & 31, kq = threadIdx.x >> 5;
  const int j = jb * 32 + jl;
  float a0 = 0, a1 = 0, a2 = 0, a3 = 0;
  const float* wp = w + (long)(k0 + kq * 16) * 1024 + j;
  #pragma unroll
  for (int k = 0; k < 16; ++k) {
    float wv = wp[(long)k * 1024];
    a0 += hl[0][kq * 16 + k] * wv;
    a1 += hl[1][kq * 16 + k] * wv;
    a2 += hl[2][kq * 16 + k] * wv;
    a3 += hl[3][kq * 16 + k] * wv;
  }
  red[kq][0][jl] = a0; red[kq][1][jl] = a1; red[kq][2][jl] = a2; red[kq][3][jl] = a3;
  __syncthreads();
  if (threadIdx.x < 128) {
    int bb = threadIdx.x >> 5, j2 = threadIdx.x & 31;
    float s = 0;
    #pragma unroll
    for (int q = 0; q < 8; ++q) s += red[q][bb][j2];
    dst[((long)kc * 4 + bb) * 1024 + jb * 32 + j2] = s;
  }
}

DEV void mlp_stats(const float* __restrict__ P, const float* __restrict__ bias,
                   float* __restrict__ st2) {
  int bb = blockIdx.x;   // 0..3
  float s = 0, q = 0;
  for (int j = threadIdx.x; j < 1024; j += 256) {
    float v = bias[j];
    #pragma unroll
    for (int kc2 = 0; kc2 < 8; ++kc2) v += P[((long)kc2 * 4 + bb) * 1024 + j];
    v = leaky(v);
    s += v; q += v * v;
  }
  #pragma unroll
  for (int off = 32; off; off >>= 1) { s += __shfl_down(s, off); q += __shfl_down(q, off); }
  __shared__ float rs2[4], rq2[4];
  int w = threadIdx.x >> 6, lane = threadIdx.x & 63;
  if (lane == 0) { rs2[w] = s; rq2[w] = q; }
  __syncthreads();
  if (threadIdx.x == 0) {
    float S = rs2[0] + rs2[1] + rs2[2] + rs2[3];
    float Q = rq2[0] + rq2[1] + rq2[2] + rq2[3];
    float mean = S * (1.f / 1024.f);
    float var = Q * (1.f / 1024.f) - mean * mean;
    st2[bb * 2] = mean;
    st2[bb * 2 + 1] = rsqrtf(var + 1e-5f);
  }
}

DEV void stage_ln(float hl[4][128], const float* __restrict__ P, const float* __restrict__ bias,
                  const float* __restrict__ st2, const float* __restrict__ gg,
                  const float* __restrict__ bbe, int k0) {
  for (int i = threadIdx.x; i < 512; i += 256) {
    int bb = i >> 7, kk = i & 127;
    int j = k0 + kk;
    float v = bias[j];
    #pragma unroll
    for (int kc2 = 0; kc2 < 8; ++kc2) v += P[((long)kc2 * 4 + bb) * 1024 + j];
    v = (leaky(v) - st2[bb * 2]) * st2[bb * 2 + 1] * gg[j] + bbe[j];
    hl[bb][kk] = v;
  }
  __syncthreads();
}

__global__ __launch_bounds__(256)
void mlp_coop(const float* __restrict__ h0,
              const float* __restrict__ w1, const float* __restrict__ b1v,
              const float* __restrict__ g1, const float* __restrict__ be1,
              const float* __restrict__ w2, const float* __restrict__ b2v,
              const float* __restrict__ g2, const float* __restrict__ be2,
              const float* __restrict__ w3, const float* __restrict__ b3v,
              float* __restrict__ pA, float* __restrict__ pB,
              float* __restrict__ st, float* __restrict__ yout) {
  cg::grid_group grid = cg::this_grid();
  __shared__ float hl[4][128];
  __shared__ float red[8][4][32];
  const int bid = blockIdx.x, jb = bid & 31, kc = bid >> 5, k0 = kc * 128;

  // G1
  for (int i = threadIdx.x; i < 512; i += 256) {
    int bb = i >> 7, kk = i & 127;
    hl[bb][kk] = h0[(bb << 10) + k0 + kk];
  }
  __syncthreads();
  gemm_core(hl, red, w1, pA, jb, kc, k0);
  grid.sync();
  if (bid < 4) mlp_stats(pA, b1v, st);
  grid.sync();
  // G2 (LN folded into staging)
  stage_ln(hl, pA, b1v, st, g1, be1, k0);
  gemm_core(hl, red, w2, pB, jb, kc, k0);
  grid.sync();
  if (bid < 4) mlp_stats(pB, b2v, st + 8);
  grid.sync();
  // G3
  stage_ln(hl, pB, b2v, st + 8, g2, be2, k0);
  gemm_core(hl, red, w3, pA, jb, kc, k0);
  grid.sync();
  if (bid < 16) {
    int i = bid * 256 + threadIdx.x;
    int bb = i >> 10, j = i & 1023;
    float v = b3v[j];
    #pragma unroll
    for (int kc2 = 0; kc2 < 8; ++kc2) v += pA[((long)kc2 * 4 + bb) * 1024 + j];
    yout[i] = v;
  }
}

// ---------------- implicit-GEMM conv1d via MFMA bf16 ----------------
template<int UPS, int SPLITK>
__global__ __launch_bounds__(256, 2)
void conv_mfma(const unsigned short* __restrict__ act,
               const unsigned short* __restrict__ wpack,
               float* __restrict__ outp,
               int Cin, int Cout, int Tout) {
  constexpr int NC = (UPS == 1) ? 70 : 18;
  const int Tin = Tout / UPS;
  const int cpb = Cin / SPLITK;
  const int ncib = cpb >> 5;
  const int nCibTot = Cin >> 5;
  const int nco = Cout >> 6, nt = Tout >> 6;

  int bid = blockIdx.x;
  const int sk = bid % SPLITK; bid /= SPLITK;
  const int tt = bid % nt;  bid /= nt;
  const int cot = bid % nco; bid /= nco;
  const int b = bid;
  const int t0 = tt << 6, co0 = cot << 6;
  const int ci0 = sk * cpb;

  extern __shared__ unsigned short lin[];    // [ncib][NC][40]

  const unsigned short* actb = act + ((long)b * Cin + ci0) * Tin;
  const int u_base = (UPS == 1) ? (t0 - 3) : ((t0 >> 2) - 1);
  const int total = cpb * NC;
  for (int i = threadIdx.x; i < total; i += 256) {
    int ci = i / NC, ul = i - ci * NC;
    int u = u_base + ul;
    unsigned short v = 0;
    if (u >= 0 && u < Tin) v = actb[(long)ci * Tin + u];
    lin[((ci >> 5) * NC + ul) * 40 + (ci & 31)] = v;
  }
  __syncthreads();

  const int lane = threadIdx.x & 63, w = threadIdx.x >> 6;
  const int m = lane & 15, g = lane >> 4;

  int boff[28];
  #pragma unroll
  for (int s = 0; s < 4; ++s) {
    #pragma unroll
    for (int k = 0; k < 7; ++k) {
      int row = (UPS == 1) ? (s * 16 + m + k)
                           : (s * 4 + ((m + k + 9) >> 2) - 2);
      boff[s * 7 + k] = row * 40 + g * 8;
    }
  }

  const long wlane = ((long)(co0 + w * 16 + m) * 4 + g) * 8;

  f32x4 acc[4];
  #pragma unroll
  for (int s = 0; s < 4; ++s) { acc[s][0] = 0.f; acc[s][1] = 0.f; acc[s][2] = 0.f; acc[s][3] = 0.f; }

  for (int cib = 0; cib < ncib; ++cib) {
    const unsigned short* lb = lin + cib * (NC * 40);
    const int cg = (ci0 >> 5) + cib;
    sh8 a[7];
    #pragma unroll
    for (int k = 0; k < 7; ++k)
      a[k] = *(const sh8*)(wpack + (long)(k * nCibTot + cg) * Cout * 32 + wlane);
    #pragma unroll
    for (int k = 0; k < 7; ++k) {
      #pragma unroll
      for (int s = 0; s < 4; ++s) {
        sh8 bfr = *(const sh8*)(lb + boff[s * 7 + k]);
        acc[s] = __builtin_amdgcn_mfma_f32_16x16x32_bf16(a[k], bfr, acc[s], 0, 0, 0);
      }
    }
  }

  float* op = outp + (((long)sk * 4 + b) * Cout + (co0 + w * 16 + g * 4)) * (long)Tout + t0 + m;
  #pragma unroll
  for (int r = 0; r < 4; ++r) {
    #pragma unroll
    for (int s = 0; s < 4; ++s)
      op[(long)r * Tout + s * 16] = acc[s][r];
  }
}

// ---------------- cooperative bn: sum split-K (regs) -> stats -> apply+leaky+bf16 ----------------
// grid 1024 x 256. Values held in registers across the grid sync (single pbuf pass).
template<int VPT, int SK, int TSH, int SEGSH>
__global__ __launch_bounds__(256)
void bn_coop(const float* __restrict__ p, const float* __restrict__ g,
             const float* __restrict__ be, unsigned short* __restrict__ obf,
             float* __restrict__ psum, int C) {
  cg::grid_group grid = cg::this_grid();
  const int E = (C << TSH) * 4;
  const long i0 = ((long)blockIdx.x * 256 + threadIdx.x) * VPT;
  float v[VPT];
  float s = 0, q = 0;
  #pragma unroll
  for (int j = 0; j < VPT; ++j) {
    float t = p[i0 + j];
    #pragma unroll
    for (int k = 1; k < SK; ++k) t += p[i0 + j + (long)k * E];
    v[j] = t; s += t; q += t * t;
  }
  #pragma unroll
  for (int off = 32; off; off >>= 1) { s += __shfl_down(s, off); q += __shfl_down(q, off); }
  __shared__ float rs[4], rq[4];
  const int w = threadIdx.x >> 6, lane = threadIdx.x & 63;
  if (lane == 0) { rs[w] = s; rq[w] = q; }
  __syncthreads();
  if (threadIdx.x == 0) {
    constexpr int CHUNK = 256 * VPT;
    constexpr int NSEG_BLK = (CHUNK >> SEGSH) ? (CHUNK >> SEGSH) : 1;
    constexpr int WPS = 4 / NSEG_BLK;   // waves per segment
    const long bseg = ((long)blockIdx.x * CHUNK) >> SEGSH;
    #pragma unroll
    for (int si = 0; si < NSEG_BLK; ++si) {
      float S = 0, Q = 0;
      #pragma unroll
      for (int ww = 0; ww < WPS; ++ww) { S += rs[si * WPS + ww]; Q += rq[si * WPS + ww]; }
      psum[(bseg + si) * 2] = S;
      psum[(bseg + si) * 2 + 1] = Q;
    }
  }
  grid.sync();
  const int c = (int)(i0 >> TSH) & (C - 1);
  constexpr int SPR = 1 << (TSH - SEGSH);   // segments per (b,c) row
  float S = 0, Q = 0;
  #pragma unroll
  for (int b = 0; b < 4; ++b) {
    #pragma unroll
    for (int si = 0; si < SPR; ++si) {
      int idx = ((b * C + c) << (TSH - SEGSH)) + si;
      S += psum[idx * 2];
      Q += psum[idx * 2 + 1];
    }
  }
  const float n = (float)(4 << TSH);
  float mean = S / n;
  float var = Q / n - mean * mean;
  float sc = g[c] * rsqrtf(var + 1e-5f);
  float sh = be[c] - mean * sc;
  #pragma unroll
  for (int j = 0; j < VPT; ++j) obf[i0 + j] = f2bf(leaky(v[j] * sc + sh));
}

// ---------------- final conv: phase-decomposed 3-tap ----------------
__global__ __launch_bounds__(256)
void conv5_kernel(const unsigned short* __restrict__ in, const float* __restrict__ wgt,
                  const float* __restrict__ bias, float* __restrict__ out, int Tout) {
  __shared__ unsigned short sv[64 * 66];
  __shared__ float wph[64 * 13];

  const int b = blockIdx.y;
  const int u0 = blockIdx.x * 64;
  const int Tin = Tout >> 2;
  const int tid = threadIdx.x;

  {
    int ci = tid >> 2, pp = tid & 3;
    float s0 = 0, s1 = 0, s2 = 0;
    #pragma unroll
    for (int k = 0; k < 7; ++k) {
      int d = (pp - 3 + k + 4) >> 2;
      float wv = wgt[ci * 7 + k];
      if (d == 0) s0 += wv; else if (d == 1) s1 += wv; else s2 += wv;
    }
    wph[ci * 13 + pp * 3 + 0] = s0;
    wph[ci * 13 + pp * 3 + 1] = s1;
    wph[ci * 13 + pp * 3 + 2] = s2;
  }

  const unsigned short* inb = in + (long)b * 64 * Tin;
  for (int i = tid; i < 64 * 66; i += 256) {
    int ci = i / 66, uu = i - ci * 66;
    int u = u0 - 1 + uu;
    unsigned short v = 0;
    if (u >= 0 && u < Tin) v = inb[(long)ci * Tin + u];
    sv[ci * 66 + uu] = v;
  }
  __syncthreads();

  const int ul = tid >> 2;
  const int chunk = tid & 3;
  float a0 = 0, a1 = 0, a2 = 0, a3 = 0;
  #pragma unroll
  for (int cc = 0; cc < 16; ++cc) {
    int ci = chunk * 16 + cc;
    float v0 = bf2f(sv[ci * 66 + ul]);
    float v1 = bf2f(sv[ci * 66 + ul + 1]);
    float v2 = bf2f(sv[ci * 66 + ul + 2]);
    const float* wp = wph + ci * 13;
    a0 += v0 * wp[0] + v1 * wp[1];
    a1 += v0 * wp[3] + v1 * wp[4] + v2 * wp[5];
    a2 += v0 * wp[6] + v1 * wp[7] + v2 * wp[8];
    a3 += v1 * wp[10] + v2 * wp[11];
  }
  #pragma unroll
  for (int msk = 1; msk <= 2; msk <<= 1) {
    a0 += __shfl_xor(a0, msk);
    a1 += __shfl_xor(a1, msk);
    a2 += __shfl_xor(a2, msk);
    a3 += __shfl_xor(a3, msk);
  }
  if (chunk == 0) {
    float bv = bias[0];
    float4 r = make_float4(a0 + bv, a1 + bv, a2 + bv, a3 + bv);
    *(float4*)(out + (long)b * Tout + (long)(u0 + ul) * 4) = r;
  }
}

extern "C" void kernel_launch(void* const* d_in, const int* in_sizes, int n_in,
                              void* d_out, int out_size, void* d_ws, size_t ws_size,
                              hipStream_t stream) {
  const float* x     = (const float*)d_in[0];
  // d_in[1] = atoms: dead (sparse_code result unused by outputs)
  const float* ew    = (const float*)d_in[2];
  const float* eb    = (const float*)d_in[3];
  const float* w1    = (const float*)d_in[4];
  const float* b1    = (const float*)d_in[5];
  const float* g1    = (const float*)d_in[6];
  const float* be1   = (const float*)d_in[7];
  const float* w2    = (const float*)d_in[8];
  const float* b2    = (const float*)d_in[9];
  const float* g2    = (const float*)d_in[10];
  const float* be2   = (const float*)d_in[11];
  const float* w3    = (const float*)d_in[12];
  const float* b3    = (const float*)d_in[13];
  const float* up_w1 = (const float*)d_in[14];
  const float* up_b1 = (const float*)d_in[15];
  const float* bn_g1 = (const float*)d_in[16];
  const float* bn_b1 = (const float*)d_in[17];
  const float* up_w2 = (const float*)d_in[18];
  const float* up_b2 = (const float*)d_in[19];
  const float* bn_g2 = (const float*)d_in[20];
  const float* bn_b2 = (const float*)d_in[21];
  const float* up_w3 = (const float*)d_in[22];
  const float* up_b3 = (const float*)d_in[23];
  const float* bn_g3 = (const float*)d_in[24];
  const float* bn_b3 = (const float*)d_in[25];
  const float* up_w4 = (const float*)d_in[26];
  const float* up_b4 = (const float*)d_in[27];
  const float* bn_g4 = (const float*)d_in[28];
  const float* bn_b4 = (const float*)d_in[29];
  const float* up_w5 = (const float*)d_in[30];
  const float* up_b5 = (const float*)d_in[31];

  float* out = (float*)d_out;              // [0,131072) = y, [131072,135168) = ctx_out

  float* ws = (float*)d_ws;
  float* ctxb   = ws;                      // 4096
  float* pA     = ctxb + 4096;             // 32768
  float* pB     = pA + 32768;              // 32768
  float* st     = pB + 32768;              // 16
  float* psum   = st + 16;                 // 4096
  float* pbuf   = psum + 4096;             // 2097152
  unsigned short* encbf = (unsigned short*)(pbuf + 2097152);  // 524288 u16
  unsigned short* o1 = encbf + 524288;     // 262144 u16
  unsigned short* o2 = o1 + 262144;        // 524288 u16
  unsigned short* o3 = o2 + 524288;        // 1048576 u16
  unsigned short* o4 = o3 + 1048576;       // 2097152 u16
  unsigned short* wbuf = o4 + 2097152;     // 4874240 u16

  // embed (MFMA) + fused ctx + fused weight packing
  embed_mfma<<<1024, 256, 0, stream>>>(x, ew, eb, encbf, ctxb, up_w1, up_w2, up_w3, up_w4, wbuf);

  // ctx MLP: one cooperative kernel
  {
    const float* h0_ = ctxb;
    float* pA_ = pA; float* pB_ = pB; float* st_ = st;
    float* yout_ = out + 131072;
    void* args[] = {(void*)&h0_, (void*)&w1, (void*)&b1, (void*)&g1, (void*)&be1,
                    (void*)&w2, (void*)&b2, (void*)&g2, (void*)&be2,
                    (void*)&w3, (void*)&b3, (void*)&pA_, (void*)&pB_, (void*)&st_, (void*)&yout_};
    hipLaunchCooperativeKernel((void*)mlp_coop, dim3(256), dim3(256), args, 0, stream);
  }

  // ---- conv stages: conv_mfma + cooperative bn ----
  conv_mfma<1, 8><<<512, 256, 22400, stream>>>(encbf, wbuf, pbuf, 1024, 512, 128);
  {
    void (*k)(const float*, const float*, const float*, unsigned short*, float*, int) = bn_coop<1, 8, 7, 7>;
    const float* p_ = pbuf; unsigned short* o_ = o1; float* ps_ = psum; int C_ = 512;
    void* args[] = {(void*)&p_, (void*)&bn_g1, (void*)&bn_b1, (void*)&o_, (void*)&ps_, (void*)&C_};
    hipLaunchCooperativeKernel((void*)k, dim3(1024), dim3(256), args, 0, stream);
  }

  conv_mfma<4, 4><<<512, 256, 5760, stream>>>(o1, wbuf + 3670016, pbuf, 512, 256, 512);
  {
    void (*k)(const float*, const float*, const float*, unsigned short*, float*, int) = bn_coop<2, 4, 9, 9>;
    const float* p_ = pbuf; unsigned short* o_ = o2; float* ps_ = psum; int C_ = 256;
    void* args[] = {(void*)&p_, (void*)&bn_g2, (void*)&bn_b2, (void*)&o_, (void*)&ps_, (void*)&C_};
    hipLaunchCooperativeKernel((void*)k, dim3(1024), dim3(256), args, 0, stream);
  }

  conv_mfma<4, 2><<<512, 256, 5760, stream>>>(o2, wbuf + 4587520, pbuf, 256, 128, 2048);
  {
    void (*k)(const float*, const float*, const float*, unsigned short*, float*, int) = bn_coop<4, 2, 11, 10>;
    const float* p_ = pbuf; unsigned short* o_ = o3; float* ps_ = psum; int C_ = 128;
    void* args[] = {(void*)&p_, (void*)&bn_g3, (void*)&bn_b3, (void*)&o_, (void*)&ps_, (void*)&C_};
    hipLaunchCooperativeKernel((void*)k, dim3(1024), dim3(256), args, 0, stream);
  }

  conv_mfma<4, 1><<<512, 256, 5760, stream>>>(o3, wbuf + 4816896, pbuf, 128, 64, 8192);
  {
    void (*k)(const float*, const float*, const float*, unsigned short*, float*, int) = bn_coop<8, 1, 13, 11>;
    const float* p_ = pbuf; unsigned short* o_ = o4; float* ps_ = psum; int C_ = 64;
    void* args[] = {(void*)&p_, (void*)&bn_g4, (void*)&bn_b4, (void*)&o_, (void*)&ps_, (void*)&C_};
    hipLaunchCooperativeKernel((void*)k, dim3(1024), dim3(256), args, 0, stream);
  }

  // ---- stage 5: -up4-> (4,1,32768), phase-decomposed ----
  conv5_kernel<<<dim3(128, 4), 256, 0, stream>>>(o4, up_w5, up_b5, out, 32768);
}

// Round 7
// 188.941 us; speedup vs baseline: 2.5225x; 2.5225x over previous
//
#include <hip/hip_runtime.h>
#include <hip/hip_bf16.h>

using sh8   = __attribute__((ext_vector_type(8))) short;
using f32x4 = __attribute__((ext_vector_type(4))) float;

#define DEV __device__ __forceinline__

DEV float leaky(float x) { return x >= 0.f ? x : 0.2f * x; }

DEV unsigned short f2bf(float f) {  // round-to-nearest-even f32 -> bf16 bits
  unsigned u = __float_as_uint(f);
  u += 0x7FFF + ((u >> 16) & 1);
  return (unsigned short)(u >> 16);
}
DEV float bf2f(unsigned short b) { return __uint_as_float(((unsigned)b) << 16); }

// ---------------- weight packs ----------------
// 7-tap (stage 1): f32 [Cout][Cin][7] -> bf16 [7][Cin/32][Cout][32]
DEV void pack_one(const float* __restrict__ w, unsigned short* __restrict__ wp,
                  int Cout, int Cin, int tid, int nthr) {
  int n = Cout * Cin * 7;
  int nCib = Cin >> 5;
  for (int i = tid; i < n; i += nthr) {
    int co = i / (Cin * 7);
    int r  = i - co * (Cin * 7);
    int ci = r / 7;
    int k  = r - ci * 7;
    wp[((long)(k * nCib + (ci >> 5)) * Cout + co) * 32 + (ci & 31)] = f2bf(w[i]);
  }
}
// phase-decomposed 3-tap (UPS=4 stages): W3[p][d] = sum_k w[k]*[((p+k+1)>>2)==d]
// layout bf16 [p*3+d][Cin/32][Cout][32]
DEV void pack_ph(const float* __restrict__ w, unsigned short* __restrict__ wp,
                 int Cout, int Cin, int tid, int nthr) {
  int n = Cout * Cin * 12;
  int nCib = Cin >> 5;
  for (int i = tid; i < n; i += nthr) {
    int co = i / (Cin * 12);
    int r  = i - co * (Cin * 12);
    int ci = r / 12;
    int pd = r - ci * 12;
    int p = pd / 3, d = pd - p * 3;
    float s = 0.f;
    #pragma unroll
    for (int k = 0; k < 7; ++k)
      if (((p + k + 1) >> 2) == d) s += w[(co * Cin + ci) * 7 + k];
    wp[((long)(pd * nCib + (ci >> 5)) * Cout + co) * 32 + (ci & 31)] = f2bf(s);
  }
}

// ---------------- embed (MFMA GEMM) + fused ctx + fused weight packing ----------------
__global__ __launch_bounds__(256)
void embed_mfma(const float* __restrict__ x, const float* __restrict__ ew,
                const float* __restrict__ eb, unsigned short* __restrict__ encbf,
                float* __restrict__ ctx,
                const float* __restrict__ cw1, const float* __restrict__ cw2,
                const float* __restrict__ cw3, const float* __restrict__ cw4,
                unsigned short* __restrict__ wbuf) {
  if (blockIdx.x >= 512) {
    int tid = (blockIdx.x - 512) * 256 + threadIdx.x;
    int nthr = 512 * 256;
    pack_one(cw1, wbuf,           512, 1024, tid, nthr);
    pack_ph (cw2, wbuf + 3670016, 256,  512, tid, nthr);
    pack_ph (cw3, wbuf + 5242880, 128,  256, tid, nthr);
    pack_ph (cw4, wbuf + 5636096,  64,  128, tid, nthr);
    return;
  }
  __shared__ unsigned short W16[257 * 16];   // [p][f], f>=8 zeroed
  __shared__ float ctxred[4][8];
  const int tid = threadIdx.x;

  for (int i = tid; i < 257 * 16; i += 256) {
    int p = i >> 4, f = i & 15;
    W16[i] = (f < 8) ? f2bf(ew[p * 8 + f]) : (unsigned short)0;
  }
  __syncthreads();

  const int w = tid >> 6, lane = tid & 63;
  const int m = lane & 15, g = lane >> 4;

  sh8 breg[8];
  #pragma unroll
  for (int kk = 0; kk < 8; ++kk) {
    #pragma unroll
    for (int j = 0; j < 8; ++j)
      breg[kk][j] = (short)W16[(kk * 32 + g * 8 + j) * 16 + m];
  }
  const float w256 = bf2f(W16[256 * 16 + m]);
  const float ebf = (m < 8) ? eb[m] : 0.f;

  const int bid = blockIdx.x;               // 512 groups
  const long rowbase = (long)bid * 128;
  const int b = bid >> 7, band = bid & 127;

  float ctx_acc = 0.f;
  #pragma unroll
  for (int s = 0; s < 2; ++s) {
    const int t0 = w * 32 + s * 16;
    const float* xp = x + (rowbase + t0 + m) * 257;
    f32x4 acc = {0.f, 0.f, 0.f, 0.f};
    #pragma unroll
    for (int kk = 0; kk < 8; ++kk) {
      const float* xk = xp + kk * 32 + g * 8;
      sh8 afr;
      #pragma unroll
      for (int j = 0; j < 8; ++j) afr[j] = (short)f2bf(xk[j]);
      acc = __builtin_amdgcn_mfma_f32_16x16x32_bf16(afr, breg[kk], acc, 0, 0, 0);
    }
    const float* xq = x + (rowbase + t0 + g * 4) * 257 + 256;
    unsigned short pk[4];
    #pragma unroll
    for (int r = 0; r < 4; ++r) {
      float e = acc[r] + xq[(long)r * 257] * w256 + ebf;
      pk[r] = f2bf(e);
      ctx_acc += e;
    }
    if (m < 8) {
      long o = ((long)b * 1024 + m * 128 + band) * 128 + t0 + g * 4;
      *(ushort4*)(encbf + o) = make_ushort4(pk[0], pk[1], pk[2], pk[3]);
    }
  }
  ctx_acc += __shfl_xor(ctx_acc, 16);
  ctx_acc += __shfl_xor(ctx_acc, 32);
  if (lane < 8) ctxred[w][lane] = ctx_acc;
  __syncthreads();
  if (tid < 8) {
    float sv = ctxred[0][tid] + ctxred[1][tid] + ctxred[2][tid] + ctxred[3][tid];
    ctx[(long)b * 1024 + tid * 128 + band] = sv;
  }
}

// ---------------- split-K gemm: partial y = h(4,1024) @ w[k-chunk] ----------------
__global__ void gemm_p(const float* __restrict__ h, const float* __restrict__ w,
                       float* __restrict__ gpart) {
  __shared__ float hl[4][128];
  __shared__ float red[8][4][32];
  const int kc = blockIdx.y, jb = blockIdx.x, k0 = kc * 128;
  for (int i = threadIdx.x; i < 512; i += 256) {
    int bb = i >> 7, kk = i & 127;
    hl[bb][kk] = h[(bb << 10) + k0 + kk];
  }
  __syncthreads();
  const int jl = threadIdx.x & 31, kq = threadIdx.x >> 5;
  const int j = jb * 32 + jl;
  float a0 = 0, a1 = 0, a2 = 0, a3 = 0;
  const float* wp = w + (long)(k0 + kq * 16) * 1024 + j;
  #pragma unroll
  for (int k = 0; k < 16; ++k) {
    float wv = wp[(long)k * 1024];
    a0 += hl[0][kq * 16 + k] * wv;
    a1 += hl[1][kq * 16 + k] * wv;
    a2 += hl[2][kq * 16 + k] * wv;
    a3 += hl[3][kq * 16 + k] * wv;
  }
  red[kq][0][jl] = a0; red[kq][1][jl] = a1; red[kq][2][jl] = a2; red[kq][3][jl] = a3;
  __syncthreads();
  if (threadIdx.x < 128) {
    int bb = threadIdx.x >> 5, j2 = threadIdx.x & 31;
    float s = 0;
    #pragma unroll
    for (int q = 0; q < 8; ++q) s += red[q][bb][j2];
    gpart[((long)kc * 4 + bb) * 1024 + jb * 32 + j2] = s;
  }
}

// ---------------- sum split-K partials + bias + leaky + layernorm ----------------
__global__ void lnsum_kernel(const float* __restrict__ gpart, const float* __restrict__ bias,
                             const float* __restrict__ g, const float* __restrict__ be,
                             float* __restrict__ out) {
  int b = blockIdx.x;
  __shared__ float buf[1024];
  __shared__ float rs[4], rq[4];
  float s = 0, q = 0;
  #pragma unroll
  for (int i = 0; i < 4; ++i) {
    int j = threadIdx.x + i * 256;
    float v = bias[j];
    #pragma unroll
    for (int kc = 0; kc < 8; ++kc) v += gpart[((long)kc * 4 + b) * 1024 + j];
    v = leaky(v);
    buf[j] = v; s += v; q += v * v;
  }
  #pragma unroll
  for (int off = 32; off; off >>= 1) { s += __shfl_down(s, off); q += __shfl_down(q, off); }
  int wid = threadIdx.x >> 6, lane = threadIdx.x & 63;
  if (lane == 0) { rs[wid] = s; rq[wid] = q; }
  __syncthreads();
  float S = rs[0] + rs[1] + rs[2] + rs[3];
  float Q = rq[0] + rq[1] + rq[2] + rq[3];
  float mean = S * (1.f / 1024.f);
  float var = Q * (1.f / 1024.f) - mean * mean;
  float rstd = rsqrtf(var + 1e-5f);
  #pragma unroll
  for (int i = 0; i < 4; ++i) {
    int j = threadIdx.x + i * 256;
    out[b * 1024 + j] = (buf[j] - mean) * rstd * g[j] + be[j];
  }
}

// ---------------- final: ctx_out = sum partials + bias ----------------
__global__ void fin_kernel(const float* __restrict__ gpart, const float* __restrict__ bias,
                           float* __restrict__ out) {
  int i = blockIdx.x * 256 + threadIdx.x;   // 4096
  int b = i >> 10, j = i & 1023;
  float v = bias[j];
  #pragma unroll
  for (int kc = 0; kc < 8; ++kc) v += gpart[((long)kc * 4 + b) * 1024 + j];
  out[i] = v;
}

// ---------------- implicit-GEMM conv1d via MFMA bf16 (stage 1, UPS=1) ----------------
template<int UPS, int SPLITK>
__global__ __launch_bounds__(256, 2)
void conv_mfma(const unsigned short* __restrict__ act,
               const unsigned short* __restrict__ wpack,
               float* __restrict__ outp,
               int Cin, int Cout, int Tout) {
  constexpr int NC = (UPS == 1) ? 70 : 18;
  const int Tin = Tout / UPS;
  const int cpb = Cin / SPLITK;
  const int ncib = cpb >> 5;
  const int nCibTot = Cin >> 5;
  const int nco = Cout >> 6, nt = Tout >> 6;

  int bid = blockIdx.x;
  const int sk = bid % SPLITK; bid /= SPLITK;
  const int tt = bid % nt;  bid /= nt;
  const int cot = bid % nco; bid /= nco;
  const int b = bid;
  const int t0 = tt << 6, co0 = cot << 6;
  const int ci0 = sk * cpb;

  extern __shared__ unsigned short lin[];    // [ncib][NC][40]

  const unsigned short* actb = act + ((long)b * Cin + ci0) * Tin;
  const int u_base = (UPS == 1) ? (t0 - 3) : ((t0 >> 2) - 1);
  const int total = cpb * NC;
  for (int i = threadIdx.x; i < total; i += 256) {
    int ci = i / NC, ul = i - ci * NC;
    int u = u_base + ul;
    unsigned short v = 0;
    if (u >= 0 && u < Tin) v = actb[(long)ci * Tin + u];
    lin[((ci >> 5) * NC + ul) * 40 + (ci & 31)] = v;
  }
  __syncthreads();

  const int lane = threadIdx.x & 63, w = threadIdx.x >> 6;
  const int m = lane & 15, g = lane >> 4;

  int boff[28];
  #pragma unroll
  for (int s = 0; s < 4; ++s) {
    #pragma unroll
    for (int k = 0; k < 7; ++k) {
      int row = (UPS == 1) ? (s * 16 + m + k)
                           : (s * 4 + ((m + k + 9) >> 2) - 2);
      boff[s * 7 + k] = row * 40 + g * 8;
    }
  }

  const long wlane = ((long)(co0 + w * 16 + m) * 4 + g) * 8;

  f32x4 acc[4];
  #pragma unroll
  for (int s = 0; s < 4; ++s) { acc[s][0] = 0.f; acc[s][1] = 0.f; acc[s][2] = 0.f; acc[s][3] = 0.f; }

  for (int cib = 0; cib < ncib; ++cib) {
    const unsigned short* lb = lin + cib * (NC * 40);
    const int cg = (ci0 >> 5) + cib;
    sh8 a[7];
    #pragma unroll
    for (int k = 0; k < 7; ++k)
      a[k] = *(const sh8*)(wpack + (long)(k * nCibTot + cg) * Cout * 32 + wlane);
    #pragma unroll
    for (int k = 0; k < 7; ++k) {
      #pragma unroll
      for (int s = 0; s < 4; ++s) {
        sh8 bfr = *(const sh8*)(lb + boff[s * 7 + k]);
        acc[s] = __builtin_amdgcn_mfma_f32_16x16x32_bf16(a[k], bfr, acc[s], 0, 0, 0);
      }
    }
  }

  float* op = outp + (((long)sk * 4 + b) * Cout + (co0 + w * 16 + g * 4)) * (long)Tout + t0 + m;
  #pragma unroll
  for (int r = 0; r < 4; ++r) {
    #pragma unroll
    for (int s = 0; s < 4; ++s)
      op[(long)r * Tout + s * 16] = acc[s][r];
  }
}

// ---------------- phase-decomposed conv (UPS=4 stages): per-phase 3-tap GEMM ----------------
// Block: 64 co x 64 u (=256 t). Weights pre-summed into W3[p*3+d]. 40 MFMA / 12 ds_read per cib.
template<int SPLITK>
__global__ __launch_bounds__(256, 2)
void conv_ph(const unsigned short* __restrict__ act,
             const unsigned short* __restrict__ wpack,
             float* __restrict__ outp,
             int Cin, int Cout, int Tin) {
  const int Tout = Tin << 2;
  const int cpb = Cin / SPLITK;
  const int ncib = cpb >> 5;
  const int nCibTot = Cin >> 5;
  const int nco = Cout >> 6, ntu = Tin >> 6;

  int bid = blockIdx.x;
  const int sk = bid % SPLITK; bid /= SPLITK;
  const int tu = bid % ntu; bid /= ntu;
  const int cot = bid % nco; bid /= nco;
  const int b = bid;
  const int u0 = tu << 6, co0 = cot << 6;
  const int ci0 = sk * cpb;

  extern __shared__ unsigned short lin[];    // [ncib][66][40]

  const unsigned short* actb = act + ((long)b * Cin + ci0) * Tin;
  const int total = cpb * 66;
  for (int i = threadIdx.x; i < total; i += 256) {
    int ci = i / 66, r = i - ci * 66;
    int u = u0 - 1 + r;                      // zero-fill edges == conv zero-pad
    unsigned short v = 0;
    if (u >= 0 && u < Tin) v = actb[(long)ci * Tin + u];
    lin[((ci >> 5) * 66 + r) * 40 + (ci & 31)] = v;
  }
  __syncthreads();

  const int lane = threadIdx.x & 63, w = threadIdx.x >> 6;
  const int m = lane & 15, g = lane >> 4;

  int boff[4][3];
  #pragma unroll
  for (int s = 0; s < 4; ++s)
    #pragma unroll
    for (int d = 0; d < 3; ++d)
      boff[s][d] = (s * 16 + m + d) * 40 + g * 8;

  const long wlane = ((long)(co0 + w * 16 + m)) * 32 + g * 8;

  f32x4 acc[4][4];                           // [s][p]
  #pragma unroll
  for (int s = 0; s < 4; ++s)
    #pragma unroll
    for (int p = 0; p < 4; ++p) { acc[s][p][0] = 0.f; acc[s][p][1] = 0.f; acc[s][p][2] = 0.f; acc[s][p][3] = 0.f; }

  for (int cib = 0; cib < ncib; ++cib) {
    const unsigned short* lb = lin + cib * (66 * 40);
    const int cg = (ci0 >> 5) + cib;
    sh8 a[12];
    #pragma unroll
    for (int pd = 0; pd < 12; ++pd)
      a[pd] = *(const sh8*)(wpack + ((long)(pd * nCibTot + cg) * Cout) * 32 + wlane);
    #pragma unroll
    for (int s = 0; s < 4; ++s) {
      sh8 b0 = *(const sh8*)(lb + boff[s][0]);
      sh8 b1 = *(const sh8*)(lb + boff[s][1]);
      sh8 b2 = *(const sh8*)(lb + boff[s][2]);
      // skip identically-zero (p,d): p0/d2 and p3/d0
      acc[s][0] = __builtin_amdgcn_mfma_f32_16x16x32_bf16(a[0],  b0, acc[s][0], 0, 0, 0);
      acc[s][0] = __builtin_amdgcn_mfma_f32_16x16x32_bf16(a[1],  b1, acc[s][0], 0, 0, 0);
      acc[s][1] = __builtin_amdgcn_mfma_f32_16x16x32_bf16(a[3],  b0, acc[s][1], 0, 0, 0);
      acc[s][1] = __builtin_amdgcn_mfma_f32_16x16x32_bf16(a[4],  b1, acc[s][1], 0, 0, 0);
      acc[s][1] = __builtin_amdgcn_mfma_f32_16x16x32_bf16(a[5],  b2, acc[s][1], 0, 0, 0);
      acc[s][2] = __builtin_amdgcn_mfma_f32_16x16x32_bf16(a[6],  b0, acc[s][2], 0, 0, 0);
      acc[s][2] = __builtin_amdgcn_mfma_f32_16x16x32_bf16(a[7],  b1, acc[s][2], 0, 0, 0);
      acc[s][2] = __builtin_amdgcn_mfma_f32_16x16x32_bf16(a[8],  b2, acc[s][2], 0, 0, 0);
      acc[s][3] = __builtin_amdgcn_mfma_f32_16x16x32_bf16(a[10], b1, acc[s][3], 0, 0, 0);
      acc[s][3] = __builtin_amdgcn_mfma_f32_16x16x32_bf16(a[11], b2, acc[s][3], 0, 0, 0);
    }
  }

  // store: D row(co)=g*4+r, col = u (m); t = 4*(u0+s*16+m)+p -> float4 over p
  float* op = outp + (((long)sk * 4 + b) * Cout + (co0 + w * 16 + g * 4)) * (long)Tout;
  #pragma unroll
  for (int r = 0; r < 4; ++r) {
    #pragma unroll
    for (int s = 0; s < 4; ++s) {
      float4 v4 = make_float4(acc[s][0][r], acc[s][1][r], acc[s][2][r], acc[s][3][r]);
      *(float4*)(op + (long)r * Tout + ((u0 + s * 16 + m) << 2)) = v4;
    }
  }
}

// ---------------- bn stats: sum split-K (write csum) + per-(c,b) partial stats ----------------
__global__ void bnsum_kernel(const float* __restrict__ p, float* __restrict__ sp,
                             float* __restrict__ csum, int C, int T, int SK) {
  int c = blockIdx.x, b = blockIdx.y;
  long stride = (long)4 * C * T;
  const float* r = p + ((long)b * C + c) * T;
  float* cw = csum + ((long)b * C + c) * T;
  float s = 0, q = 0;
  for (int t = threadIdx.x; t < T; t += 256) {
    float v = r[t];
    for (int k = 1; k < SK; ++k) v += r[t + k * stride];
    cw[t] = v;
    s += v; q += v * v;
  }
  #pragma unroll
  for (int off = 32; off; off >>= 1) { s += __shfl_down(s, off); q += __shfl_down(q, off); }
  __shared__ float rs[4], rq[4];
  int wid = threadIdx.x >> 6, lane = threadIdx.x & 63;
  if (lane == 0) { rs[wid] = s; rq[wid] = q; }
  __syncthreads();
  if (threadIdx.x == 0) {
    sp[c * 4 + b] = rs[0] + rs[1] + rs[2] + rs[3];
    sp[C * 4 + c * 4 + b] = rq[0] + rq[1] + rq[2] + rq[3];
  }
}

// ---------------- bn finalize + leaky, emit bf16 (reads csum) ----------------
__global__ void bnapply_kernel(const float* __restrict__ csum, const float* __restrict__ sp,
                               const float* __restrict__ g, const float* __restrict__ be,
                               unsigned short* __restrict__ obf,
                               int C, int tshift, int total) {
  int i = blockIdx.x * 256 + threadIdx.x;
  if (i >= total) return;
  float v = csum[i];
  int c = (i >> tshift) & (C - 1);
  float s = sp[c * 4] + sp[c * 4 + 1] + sp[c * 4 + 2] + sp[c * 4 + 3];
  float q = sp[C * 4 + c * 4] + sp[C * 4 + c * 4 + 1] + sp[C * 4 + c * 4 + 2] + sp[C * 4 + c * 4 + 3];
  float n = (float)(4 << tshift);
  float mean = s / n;
  float var = q / n - mean * mean;
  float sc = g[c] * rsqrtf(var + 1e-5f);
  float sh = be[c] - mean * sc;
  obf[i] = f2bf(leaky(v * sc + sh));
}

// ---------------- final conv: phase-decomposed 3-tap ----------------
__global__ __launch_bounds__(256)
void conv5_kernel(const unsigned short* __restrict__ in, const float* __restrict__ wgt,
                  const float* __restrict__ bias, float* __restrict__ out, int Tout) {
  __shared__ unsigned short sv[64 * 66];
  __shared__ float wph[64 * 13];

  const int b = blockIdx.y;
  const int u0 = blockIdx.x * 64;
  const int Tin = Tout >> 2;
  const int tid = threadIdx.x;

  {
    int ci = tid >> 2, pp = tid & 3;
    float s0 = 0, s1 = 0, s2 = 0;
    #pragma unroll
    for (int k = 0; k < 7; ++k) {
      int d = (pp - 3 + k + 4) >> 2;
      float wv = wgt[ci * 7 + k];
      if (d == 0) s0 += wv; else if (d == 1) s1 += wv; else s2 += wv;
    }
    wph[ci * 13 + pp * 3 + 0] = s0;
    wph[ci * 13 + pp * 3 + 1] = s1;
    wph[ci * 13 + pp * 3 + 2] = s2;
  }

  const unsigned short* inb = in + (long)b * 64 * Tin;
  for (int i = tid; i < 64 * 66; i += 256) {
    int ci = i / 66, uu = i - ci * 66;
    int u = u0 - 1 + uu;
    unsigned short v = 0;
    if (u >= 0 && u < Tin) v = inb[(long)ci * Tin + u];
    sv[ci * 66 + uu] = v;
  }
  __syncthreads();

  const int ul = tid >> 2;
  const int chunk = tid & 3;
  float a0 = 0, a1 = 0, a2 = 0, a3 = 0;
  #pragma unroll
  for (int cc = 0; cc < 16; ++cc) {
    int ci = chunk * 16 + cc;
    float v0 = bf2f(sv[ci * 66 + ul]);
    float v1 = bf2f(sv[ci * 66 + ul + 1]);
    float v2 = bf2f(sv[ci * 66 + ul + 2]);
    const float* wp = wph + ci * 13;
    a0 += v0 * wp[0] + v1 * wp[1];
    a1 += v0 * wp[3] + v1 * wp[4] + v2 * wp[5];
    a2 += v0 * wp[6] + v1 * wp[7] + v2 * wp[8];
    a3 += v1 * wp[10] + v2 * wp[11];
  }
  #pragma unroll
  for (int msk = 1; msk <= 2; msk <<= 1) {
    a0 += __shfl_xor(a0, msk);
    a1 += __shfl_xor(a1, msk);
    a2 += __shfl_xor(a2, msk);
    a3 += __shfl_xor(a3, msk);
  }
  if (chunk == 0) {
    float bv = bias[0];
    float4 r = make_float4(a0 + bv, a1 + bv, a2 + bv, a3 + bv);
    *(float4*)(out + (long)b * Tout + (long)(u0 + ul) * 4) = r;
  }
}

extern "C" void kernel_launch(void* const* d_in, const int* in_sizes, int n_in,
                              void* d_out, int out_size, void* d_ws, size_t ws_size,
                              hipStream_t stream) {
  const float* x     = (const float*)d_in[0];
  // d_in[1] = atoms: dead (sparse_code result unused by outputs)
  const float* ew    = (const float*)d_in[2];
  const float* eb    = (const float*)d_in[3];
  const float* w1    = (const float*)d_in[4];
  const float* b1    = (const float*)d_in[5];
  const float* g1    = (const float*)d_in[6];
  const float* be1   = (const float*)d_in[7];
  const float* w2    = (const float*)d_in[8];
  const float* b2    = (const float*)d_in[9];
  const float* g2    = (const float*)d_in[10];
  const float* be2   = (const float*)d_in[11];
  const float* w3    = (const float*)d_in[12];
  const float* b3    = (const float*)d_in[13];
  const float* up_w1 = (const float*)d_in[14];
  const float* up_b1 = (const float*)d_in[15];
  const float* bn_g1 = (const float*)d_in[16];
  const float* bn_b1 = (const float*)d_in[17];
  const float* up_w2 = (const float*)d_in[18];
  const float* up_b2 = (const float*)d_in[19];
  const float* bn_g2 = (const float*)d_in[20];
  const float* bn_b2 = (const float*)d_in[21];
  const float* up_w3 = (const float*)d_in[22];
  const float* up_b3 = (const float*)d_in[23];
  const float* bn_g3 = (const float*)d_in[24];
  const float* bn_b3 = (const float*)d_in[25];
  const float* up_w4 = (const float*)d_in[26];
  const float* up_b4 = (const float*)d_in[27];
  const float* bn_g4 = (const float*)d_in[28];
  const float* bn_b4 = (const float*)d_in[29];
  const float* up_w5 = (const float*)d_in[30];
  const float* up_b5 = (const float*)d_in[31];

  float* out = (float*)d_out;              // [0,131072) = y, [131072,135168) = ctx_out

  float* ws = (float*)d_ws;
  float* ctxb   = ws;                      // 4096
  float* gpart  = ctxb + 4096;             // 32768
  float* t2     = gpart + 32768;           // 4096
  float* statsp = t2 + 4096;               // 4096
  float* csum   = statsp + 4096;           // 2097152
  float* pbuf   = csum + 2097152;          // 4194304 (max SK*E = 16.8 MB)
  unsigned short* encbf = (unsigned short*)(pbuf + 4194304);  // 524288 u16
  unsigned short* o1 = encbf + 524288;     // 262144 u16
  unsigned short* o2 = o1 + 262144;        // 524288 u16
  unsigned short* o3 = o2 + 524288;        // 1048576 u16
  unsigned short* o4 = o3 + 1048576;       // 2097152 u16
  unsigned short* wbuf = o4 + 2097152;     // 5734400 u16

  // embed (MFMA) + fused ctx + fused weight packing (7-tap s1, phase s2-s4)
  embed_mfma<<<1024, 256, 0, stream>>>(x, ew, eb, encbf, ctxb, up_w1, up_w2, up_w3, up_w4, wbuf);

  // ctx MLP (split-K gemms, deterministic partial sums)
  gemm_p<<<dim3(32, 8), 256, 0, stream>>>(ctxb, w1, gpart);
  lnsum_kernel<<<4, 256, 0, stream>>>(gpart, b1, g1, be1, t2);
  gemm_p<<<dim3(32, 8), 256, 0, stream>>>(t2, w2, gpart);
  lnsum_kernel<<<4, 256, 0, stream>>>(gpart, b2, g2, be2, t2);
  gemm_p<<<dim3(32, 8), 256, 0, stream>>>(t2, w3, gpart);
  fin_kernel<<<16, 256, 0, stream>>>(gpart, b3, out + 131072);

  // ---- stage 1: (4,1024,128) -> (4,512,128), UPS=1, SK=8 ----
  conv_mfma<1, 8><<<512, 256, 22400, stream>>>(encbf, wbuf, pbuf, 1024, 512, 128);
  bnsum_kernel<<<dim3(512, 4), 256, 0, stream>>>(pbuf, statsp, csum, 512, 128, 8);
  bnapply_kernel<<<1024, 256, 0, stream>>>(csum, statsp, bn_g1, bn_b1, o1, 512, 7, 262144);

  // ---- stage 2: (4,512,128) -ph-> (4,256,512), SK=8 ----
  conv_ph<8><<<256, 256, 10560, stream>>>(o1, wbuf + 3670016, pbuf, 512, 256, 128);
  bnsum_kernel<<<dim3(256, 4), 256, 0, stream>>>(pbuf, statsp, csum, 256, 512, 8);
  bnapply_kernel<<<2048, 256, 0, stream>>>(csum, statsp, bn_g2, bn_b2, o2, 256, 9, 524288);

  // ---- stage 3: (4,256,512) -ph-> (4,128,2048), SK=4 ----
  conv_ph<4><<<256, 256, 10560, stream>>>(o2, wbuf + 5242880, pbuf, 256, 128, 512);
  bnsum_kernel<<<dim3(128, 4), 256, 0, stream>>>(pbuf, statsp, csum, 128, 2048, 4);
  bnapply_kernel<<<4096, 256, 0, stream>>>(csum, statsp, bn_g3, bn_b3, o3, 128, 11, 1048576);

  // ---- stage 4: (4,128,2048) -ph-> (4,64,8192), SK=2 ----
  conv_ph<2><<<256, 256, 10560, stream>>>(o3, wbuf + 5636096, pbuf, 128, 64, 2048);
  bnsum_kernel<<<dim3(64, 4), 256, 0, stream>>>(pbuf, statsp, csum, 64, 8192, 2);
  bnapply_kernel<<<8192, 256, 0, stream>>>(csum, statsp, bn_g4, bn_b4, o4, 64, 13, 2097152);

  // ---- stage 5: (4,64,8192) -ph-> (4,1,32768) ----
  conv5_kernel<<<dim3(128, 4), 256, 0, stream>>>(o4, up_w5, up_b5, out, 32768);
}

// Round 8
// 178.442 us; speedup vs baseline: 2.6709x; 1.0588x over previous
//
#include <hip/hip_runtime.h>
#include <hip/hip_bf16.h>

using sh8   = __attribute__((ext_vector_type(8))) short;
using sh4   = __attribute__((ext_vector_type(4))) short;
using f32x4 = __attribute__((ext_vector_type(4))) float;

#define DEV __device__ __forceinline__

DEV float leaky(float x) { return x >= 0.f ? x : 0.2f * x; }

DEV unsigned short f2bf(float f) {  // round-to-nearest-even f32 -> bf16 bits
  unsigned u = __float_as_uint(f);
  u += 0x7FFF + ((u >> 16) & 1);
  return (unsigned short)(u >> 16);
}
DEV float bf2f(unsigned short b) { return __uint_as_float(((unsigned)b) << 16); }

// ---------------- weight packing (templated: all dims pow2 -> shifts) ----------------
// 7-tap: f32 [Cout][Cin][7] -> bf16 [7][Cin/32][Cout][32]
template<int Cout, int Cin>
DEV void pack7_body(const float* __restrict__ w, unsigned short* __restrict__ wp, int blk) {
  constexpr long plane = (long)(Cin >> 5) * Cout * 32;
  int tid = blk * 256 + threadIdx.x;
  if (tid >= Cout * Cin) return;
  int co = tid / Cin, ci = tid - co * Cin;
  const float* src = w + (long)tid * 7;
  unsigned short* dst = wp + ((long)(ci >> 5) * Cout + co) * 32 + (ci & 31);
  #pragma unroll
  for (int k = 0; k < 7; ++k) dst[k * plane] = f2bf(src[k]);
}
// phase-decomposed 3-tap: W3[p][d] = sum_k w[k]*[((p+k+1)>>2)==d]; bf16 [p*3+d][Cin/32][Cout][32]
template<int Cout, int Cin>
DEV void packph_body(const float* __restrict__ w, unsigned short* __restrict__ wp, int blk) {
  constexpr long plane = (long)(Cin >> 5) * Cout * 32;
  int tid = blk * 256 + threadIdx.x;
  if (tid >= Cout * Cin) return;
  int co = tid / Cin, ci = tid - co * Cin;
  float wk[7];
  #pragma unroll
  for (int k = 0; k < 7; ++k) wk[k] = w[(long)tid * 7 + k];
  unsigned short* dst = wp + ((long)(ci >> 5) * Cout + co) * 32 + (ci & 31);
  #pragma unroll
  for (int p = 0; p < 4; ++p) {
    #pragma unroll
    for (int d = 0; d < 3; ++d) {
      float s = 0.f;
      #pragma unroll
      for (int k = 0; k < 7; ++k) if (((p + k + 1) >> 2) == d) s += wk[k];
      dst[(p * 3 + d) * plane] = f2bf(s);
    }
  }
}
__global__ __launch_bounds__(256)
void pack_all(const float* __restrict__ w1, const float* __restrict__ w2,
              const float* __restrict__ w3, const float* __restrict__ w4,
              unsigned short* __restrict__ wbuf) {
  int blk = blockIdx.x;
  if (blk < 2048)      pack7_body<512, 1024>(w1, wbuf, blk);
  else if (blk < 2560) packph_body<256, 512>(w2, wbuf + 3670016, blk - 2048);
  else if (blk < 2688) packph_body<128, 256>(w3, wbuf + 5242880, blk - 2560);
  else                 packph_body<64, 128>(w4, wbuf + 5636096, blk - 2688);
}

// ---------------- embed v4: MFMA GEMM, LDS-staged bf16 x, fused ctx ----------------
// Block = one (b,band) = 128 rows, processed as 2 phases of 64 rows sharing one LDS buffer.
__global__ __launch_bounds__(256)
void embed_mfma(const float* __restrict__ x, const float* __restrict__ ew,
                const float* __restrict__ eb, unsigned short* __restrict__ encbf,
                float* __restrict__ ctx) {
  __shared__ unsigned short W16[257 * 16];   // [p][f], f>=8 zeroed
  __shared__ unsigned short sv[64 * 260];    // 64 rows x 257 bf16, stride 260 (b64-aligned)
  __shared__ float ctxred[4][8];
  const int tid = threadIdx.x;
  const int bid = blockIdx.x;                // 512 groups
  const long rowbase = (long)bid * 128;
  const int b = bid >> 7, band = bid & 127;

  for (int i = tid; i < 257 * 16; i += 256) {
    int p = i >> 4, f = i & 15;
    W16[i] = (f < 8) ? f2bf(ew[p * 8 + f]) : (unsigned short)0;
  }
  {
    const float* src = x + rowbase * 257;    // phase-0 rows, coalesced
    for (int i = tid; i < 16448; i += 256) {
      int r = i / 257, c = i - r * 257;
      sv[r * 260 + c] = f2bf(src[i]);
    }
  }
  __syncthreads();

  const int w = tid >> 6, lane = tid & 63;
  const int m = lane & 15, g = lane >> 4;

  sh8 breg[8];
  #pragma unroll
  for (int kk = 0; kk < 8; ++kk) {
    #pragma unroll
    for (int j = 0; j < 8; ++j)
      breg[kk][j] = (short)W16[(kk * 32 + g * 8 + j) * 16 + m];
  }
  const float w256 = bf2f(W16[256 * 16 + m]);
  const float ebf = (m < 8) ? eb[m] : 0.f;

  float ctx_acc = 0.f;
  #pragma unroll
  for (int ph = 0; ph < 2; ++ph) {
    if (ph) {
      __syncthreads();                       // all phase-0 reads done
      const float* src = x + (rowbase + 64) * 257;
      for (int i = tid; i < 16448; i += 256) {
        int r = i / 257, c = i - r * 257;
        sv[r * 260 + c] = f2bf(src[i]);
      }
      __syncthreads();
    }
    f32x4 acc = {0.f, 0.f, 0.f, 0.f};
    const unsigned short* bp0 = sv + (w * 16 + m) * 260 + g * 8;
    #pragma unroll
    for (int kk = 0; kk < 8; ++kk) {
      sh4 lo = *(const sh4*)(bp0 + kk * 32);
      sh4 hi = *(const sh4*)(bp0 + kk * 32 + 4);
      sh8 afr;
      afr[0] = lo[0]; afr[1] = lo[1]; afr[2] = lo[2]; afr[3] = lo[3];
      afr[4] = hi[0]; afr[5] = hi[1]; afr[6] = hi[2]; afr[7] = hi[3];
      acc = __builtin_amdgcn_mfma_f32_16x16x32_bf16(afr, breg[kk], acc, 0, 0, 0);
    }
    const int t0 = ph * 64 + w * 16;
    unsigned short pk[4];
    #pragma unroll
    for (int r = 0; r < 4; ++r) {
      float xv = bf2f(sv[(w * 16 + g * 4 + r) * 260 + 256]);
      float e = acc[r] + xv * w256 + ebf;    // m>=8 lanes: exact 0
      pk[r] = f2bf(e);
      ctx_acc += e;
    }
    if (m < 8) {
      long o = ((long)b * 1024 + m * 128 + band) * 128 + t0 + g * 4;
      *(ushort4*)(encbf + o) = make_ushort4(pk[0], pk[1], pk[2], pk[3]);
    }
  }
  ctx_acc += __shfl_xor(ctx_acc, 16);
  ctx_acc += __shfl_xor(ctx_acc, 32);
  if (lane < 8) ctxred[w][lane] = ctx_acc;
  __syncthreads();
  if (tid < 8) {
    float sv2 = ctxred[0][tid] + ctxred[1][tid] + ctxred[2][tid] + ctxred[3][tid];
    ctx[(long)b * 1024 + tid * 128 + band] = sv2;
  }
}

// ---------------- split-K gemm: partial y = h(4,1024) @ w[k-chunk] ----------------
__global__ void gemm_p(const float* __restrict__ h, const float* __restrict__ w,
                       float* __restrict__ gpart) {
  __shared__ float hl[4][128];
  __shared__ float red[8][4][32];
  const int kc = blockIdx.y, jb = blockIdx.x, k0 = kc * 128;
  for (int i = threadIdx.x; i < 512; i += 256) {
    int bb = i >> 7, kk = i & 127;
    hl[bb][kk] = h[(bb << 10) + k0 + kk];
  }
  __syncthreads();
  const int jl = threadIdx.x & 31, kq = threadIdx.x >> 5;
  const int j = jb * 32 + jl;
  float a0 = 0, a1 = 0, a2 = 0, a3 = 0;
  const float* wp = w + (long)(k0 + kq * 16) * 1024 + j;
  #pragma unroll
  for (int k = 0; k < 16; ++k) {
    float wv = wp[(long)k * 1024];
    a0 += hl[0][kq * 16 + k] * wv;
    a1 += hl[1][kq * 16 + k] * wv;
    a2 += hl[2][kq * 16 + k] * wv;
    a3 += hl[3][kq * 16 + k] * wv;
  }
  red[kq][0][jl] = a0; red[kq][1][jl] = a1; red[kq][2][jl] = a2; red[kq][3][jl] = a3;
  __syncthreads();
  if (threadIdx.x < 128) {
    int bb = threadIdx.x >> 5, j2 = threadIdx.x & 31;
    float s = 0;
    #pragma unroll
    for (int q = 0; q < 8; ++q) s += red[q][bb][j2];
    gpart[((long)kc * 4 + bb) * 1024 + jb * 32 + j2] = s;
  }
}

// ---------------- sum split-K partials + bias + leaky + layernorm ----------------
__global__ void lnsum_kernel(const float* __restrict__ gpart, const float* __restrict__ bias,
                             const float* __restrict__ g, const float* __restrict__ be,
                             float* __restrict__ out) {
  int b = blockIdx.x;
  __shared__ float buf[1024];
  __shared__ float rs[4], rq[4];
  float s = 0, q = 0;
  #pragma unroll
  for (int i = 0; i < 4; ++i) {
    int j = threadIdx.x + i * 256;
    float v = bias[j];
    #pragma unroll
    for (int kc = 0; kc < 8; ++kc) v += gpart[((long)kc * 4 + b) * 1024 + j];
    v = leaky(v);
    buf[j] = v; s += v; q += v * v;
  }
  #pragma unroll
  for (int off = 32; off; off >>= 1) { s += __shfl_down(s, off); q += __shfl_down(q, off); }
  int wid = threadIdx.x >> 6, lane = threadIdx.x & 63;
  if (lane == 0) { rs[wid] = s; rq[wid] = q; }
  __syncthreads();
  float S = rs[0] + rs[1] + rs[2] + rs[3];
  float Q = rq[0] + rq[1] + rq[2] + rq[3];
  float mean = S * (1.f / 1024.f);
  float var = Q * (1.f / 1024.f) - mean * mean;
  float rstd = rsqrtf(var + 1e-5f);
  #pragma unroll
  for (int i = 0; i < 4; ++i) {
    int j = threadIdx.x + i * 256;
    out[b * 1024 + j] = (buf[j] - mean) * rstd * g[j] + be[j];
  }
}

// ---------------- final: ctx_out = sum partials + bias ----------------
__global__ void fin_kernel(const float* __restrict__ gpart, const float* __restrict__ bias,
                           float* __restrict__ out) {
  int i = blockIdx.x * 256 + threadIdx.x;   // 4096
  int b = i >> 10, j = i & 1023;
  float v = bias[j];
  #pragma unroll
  for (int kc = 0; kc < 8; ++kc) v += gpart[((long)kc * 4 + b) * 1024 + j];
  out[i] = v;
}

// ---------------- implicit-GEMM conv1d via MFMA bf16 (stage 1, UPS=1) ----------------
template<int UPS, int SPLITK>
__global__ __launch_bounds__(256, 2)
void conv_mfma(const unsigned short* __restrict__ act,
               const unsigned short* __restrict__ wpack,
               float* __restrict__ outp,
               int Cin, int Cout, int Tout) {
  constexpr int NC = (UPS == 1) ? 70 : 18;
  const int Tin = Tout / UPS;
  const int cpb = Cin / SPLITK;
  const int ncib = cpb >> 5;
  const int nCibTot = Cin >> 5;
  const int nco = Cout >> 6, nt = Tout >> 6;

  int bid = blockIdx.x;
  const int sk = bid % SPLITK; bid /= SPLITK;
  const int tt = bid % nt;  bid /= nt;
  const int cot = bid % nco; bid /= nco;
  const int b = bid;
  const int t0 = tt << 6, co0 = cot << 6;
  const int ci0 = sk * cpb;

  extern __shared__ unsigned short lin[];    // [ncib][NC][40]

  const unsigned short* actb = act + ((long)b * Cin + ci0) * Tin;
  const int u_base = (UPS == 1) ? (t0 - 3) : ((t0 >> 2) - 1);
  const int total = cpb * NC;
  for (int i = threadIdx.x; i < total; i += 256) {
    int ci = i / NC, ul = i - ci * NC;
    int u = u_base + ul;
    unsigned short v = 0;
    if (u >= 0 && u < Tin) v = actb[(long)ci * Tin + u];
    lin[((ci >> 5) * NC + ul) * 40 + (ci & 31)] = v;
  }
  __syncthreads();

  const int lane = threadIdx.x & 63, w = threadIdx.x >> 6;
  const int m = lane & 15, g = lane >> 4;

  int boff[28];
  #pragma unroll
  for (int s = 0; s < 4; ++s) {
    #pragma unroll
    for (int k = 0; k < 7; ++k) {
      int row = (UPS == 1) ? (s * 16 + m + k)
                           : (s * 4 + ((m + k + 9) >> 2) - 2);
      boff[s * 7 + k] = row * 40 + g * 8;
    }
  }

  const long wlane = ((long)(co0 + w * 16 + m) * 4 + g) * 8;

  f32x4 acc[4];
  #pragma unroll
  for (int s = 0; s < 4; ++s) { acc[s][0] = 0.f; acc[s][1] = 0.f; acc[s][2] = 0.f; acc[s][3] = 0.f; }

  for (int cib = 0; cib < ncib; ++cib) {
    const unsigned short* lb = lin + cib * (NC * 40);
    const int cg = (ci0 >> 5) + cib;
    sh8 a[7];
    #pragma unroll
    for (int k = 0; k < 7; ++k)
      a[k] = *(const sh8*)(wpack + (long)(k * nCibTot + cg) * Cout * 32 + wlane);
    #pragma unroll
    for (int k = 0; k < 7; ++k) {
      #pragma unroll
      for (int s = 0; s < 4; ++s) {
        sh8 bfr = *(const sh8*)(lb + boff[s * 7 + k]);
        acc[s] = __builtin_amdgcn_mfma_f32_16x16x32_bf16(a[k], bfr, acc[s], 0, 0, 0);
      }
    }
  }

  float* op = outp + (((long)sk * 4 + b) * Cout + (co0 + w * 16 + g * 4)) * (long)Tout + t0 + m;
  #pragma unroll
  for (int r = 0; r < 4; ++r) {
    #pragma unroll
    for (int s = 0; s < 4; ++s)
      op[(long)r * Tout + s * 16] = acc[s][r];
  }
}

// ---------------- phase-decomposed conv (UPS=4 stages): per-phase 3-tap GEMM ----------------
template<int SPLITK>
__global__ __launch_bounds__(256, 2)
void conv_ph(const unsigned short* __restrict__ act,
             const unsigned short* __restrict__ wpack,
             float* __restrict__ outp,
             int Cin, int Cout, int Tin) {
  const int Tout = Tin << 2;
  const int cpb = Cin / SPLITK;
  const int ncib = cpb >> 5;
  const int nCibTot = Cin >> 5;
  const int nco = Cout >> 6, ntu = Tin >> 6;

  int bid = blockIdx.x;
  const int sk = bid % SPLITK; bid /= SPLITK;
  const int tu = bid % ntu; bid /= ntu;
  const int cot = bid % nco; bid /= nco;
  const int b = bid;
  const int u0 = tu << 6, co0 = cot << 6;
  const int ci0 = sk * cpb;

  extern __shared__ unsigned short lin[];    // [ncib][66][40]

  const unsigned short* actb = act + ((long)b * Cin + ci0) * Tin;
  const int total = cpb * 66;
  for (int i = threadIdx.x; i < total; i += 256) {
    int ci = i / 66, r = i - ci * 66;
    int u = u0 - 1 + r;
    unsigned short v = 0;
    if (u >= 0 && u < Tin) v = actb[(long)ci * Tin + u];
    lin[((ci >> 5) * 66 + r) * 40 + (ci & 31)] = v;
  }
  __syncthreads();

  const int lane = threadIdx.x & 63, w = threadIdx.x >> 6;
  const int m = lane & 15, g = lane >> 4;

  int boff[4][3];
  #pragma unroll
  for (int s = 0; s < 4; ++s)
    #pragma unroll
    for (int d = 0; d < 3; ++d)
      boff[s][d] = (s * 16 + m + d) * 40 + g * 8;

  const long wlane = ((long)(co0 + w * 16 + m)) * 32 + g * 8;

  f32x4 acc[4][4];                           // [s][p]
  #pragma unroll
  for (int s = 0; s < 4; ++s)
    #pragma unroll
    for (int p = 0; p < 4; ++p) { acc[s][p][0] = 0.f; acc[s][p][1] = 0.f; acc[s][p][2] = 0.f; acc[s][p][3] = 0.f; }

  for (int cib = 0; cib < ncib; ++cib) {
    const unsigned short* lb = lin + cib * (66 * 40);
    const int cg = (ci0 >> 5) + cib;
    sh8 a[12];
    #pragma unroll
    for (int pd = 0; pd < 12; ++pd)
      a[pd] = *(const sh8*)(wpack + ((long)(pd * nCibTot + cg) * Cout) * 32 + wlane);
    #pragma unroll
    for (int s = 0; s < 4; ++s) {
      sh8 b0 = *(const sh8*)(lb + boff[s][0]);
      sh8 b1 = *(const sh8*)(lb + boff[s][1]);
      sh8 b2 = *(const sh8*)(lb + boff[s][2]);
      acc[s][0] = __builtin_amdgcn_mfma_f32_16x16x32_bf16(a[0],  b0, acc[s][0], 0, 0, 0);
      acc[s][0] = __builtin_amdgcn_mfma_f32_16x16x32_bf16(a[1],  b1, acc[s][0], 0, 0, 0);
      acc[s][1] = __builtin_amdgcn_mfma_f32_16x16x32_bf16(a[3],  b0, acc[s][1], 0, 0, 0);
      acc[s][1] = __builtin_amdgcn_mfma_f32_16x16x32_bf16(a[4],  b1, acc[s][1], 0, 0, 0);
      acc[s][1] = __builtin_amdgcn_mfma_f32_16x16x32_bf16(a[5],  b2, acc[s][1], 0, 0, 0);
      acc[s][2] = __builtin_amdgcn_mfma_f32_16x16x32_bf16(a[6],  b0, acc[s][2], 0, 0, 0);
      acc[s][2] = __builtin_amdgcn_mfma_f32_16x16x32_bf16(a[7],  b1, acc[s][2], 0, 0, 0);
      acc[s][2] = __builtin_amdgcn_mfma_f32_16x16x32_bf16(a[8],  b2, acc[s][2], 0, 0, 0);
      acc[s][3] = __builtin_amdgcn_mfma_f32_16x16x32_bf16(a[10], b1, acc[s][3], 0, 0, 0);
      acc[s][3] = __builtin_amdgcn_mfma_f32_16x16x32_bf16(a[11], b2, acc[s][3], 0, 0, 0);
    }
  }

  float* op = outp + (((long)sk * 4 + b) * Cout + (co0 + w * 16 + g * 4)) * (long)Tout;
  #pragma unroll
  for (int r = 0; r < 4; ++r) {
    #pragma unroll
    for (int s = 0; s < 4; ++s) {
      float4 v4 = make_float4(acc[s][0][r], acc[s][1][r], acc[s][2][r], acc[s][3][r]);
      *(float4*)(op + (long)r * Tout + ((u0 + s * 16 + m) << 2)) = v4;
    }
  }
}

// ---------------- bn stats: sum split-K (write csum) + per-(c,b) partial stats ----------------
__global__ void bnsum_kernel(const float* __restrict__ p, float* __restrict__ sp,
                             float* __restrict__ csum, int C, int T, int SK) {
  int c = blockIdx.x, b = blockIdx.y;
  long stride = (long)4 * C * T;
  const float* r = p + ((long)b * C + c) * T;
  float* cw = csum + ((long)b * C + c) * T;
  float s = 0, q = 0;
  for (int t = threadIdx.x; t < T; t += 256) {
    float v = r[t];
    for (int k = 1; k < SK; ++k) v += r[t + k * stride];
    cw[t] = v;
    s += v; q += v * v;
  }
  #pragma unroll
  for (int off = 32; off; off >>= 1) { s += __shfl_down(s, off); q += __shfl_down(q, off); }
  __shared__ float rs[4], rq[4];
  int wid = threadIdx.x >> 6, lane = threadIdx.x & 63;
  if (lane == 0) { rs[wid] = s; rq[wid] = q; }
  __syncthreads();
  if (threadIdx.x == 0) {
    sp[c * 4 + b] = rs[0] + rs[1] + rs[2] + rs[3];
    sp[C * 4 + c * 4 + b] = rq[0] + rq[1] + rq[2] + rq[3];
  }
}

// ---------------- bn finalize + leaky, emit bf16 (reads csum) ----------------
__global__ void bnapply_kernel(const float* __restrict__ csum, const float* __restrict__ sp,
                               const float* __restrict__ g, const float* __restrict__ be,
                               unsigned short* __restrict__ obf,
                               int C, int tshift, int total) {
  int i = blockIdx.x * 256 + threadIdx.x;
  if (i >= total) return;
  float v = csum[i];
  int c = (i >> tshift) & (C - 1);
  float s = sp[c * 4] + sp[c * 4 + 1] + sp[c * 4 + 2] + sp[c * 4 + 3];
  float q = sp[C * 4 + c * 4] + sp[C * 4 + c * 4 + 1] + sp[C * 4 + c * 4 + 2] + sp[C * 4 + c * 4 + 3];
  float n = (float)(4 << tshift);
  float mean = s / n;
  float var = q / n - mean * mean;
  float sc = g[c] * rsqrtf(var + 1e-5f);
  float sh = be[c] - mean * sc;
  obf[i] = f2bf(leaky(v * sc + sh));
}

// ---------------- final conv: phase-decomposed 3-tap ----------------
__global__ __launch_bounds__(256)
void conv5_kernel(const unsigned short* __restrict__ in, const float* __restrict__ wgt,
                  const float* __restrict__ bias, float* __restrict__ out, int Tout) {
  __shared__ unsigned short sv[64 * 66];
  __shared__ float wph[64 * 13];

  const int b = blockIdx.y;
  const int u0 = blockIdx.x * 64;
  const int Tin = Tout >> 2;
  const int tid = threadIdx.x;

  {
    int ci = tid >> 2, pp = tid & 3;
    float s0 = 0, s1 = 0, s2 = 0;
    #pragma unroll
    for (int k = 0; k < 7; ++k) {
      int d = (pp - 3 + k + 4) >> 2;
      float wv = wgt[ci * 7 + k];
      if (d == 0) s0 += wv; else if (d == 1) s1 += wv; else s2 += wv;
    }
    wph[ci * 13 + pp * 3 + 0] = s0;
    wph[ci * 13 + pp * 3 + 1] = s1;
    wph[ci * 13 + pp * 3 + 2] = s2;
  }

  const unsigned short* inb = in + (long)b * 64 * Tin;
  for (int i = tid; i < 64 * 66; i += 256) {
    int ci = i / 66, uu = i - ci * 66;
    int u = u0 - 1 + uu;
    unsigned short v = 0;
    if (u >= 0 && u < Tin) v = inb[(long)ci * Tin + u];
    sv[ci * 66 + uu] = v;
  }
  __syncthreads();

  const int ul = tid >> 2;
  const int chunk = tid & 3;
  float a0 = 0, a1 = 0, a2 = 0, a3 = 0;
  #pragma unroll
  for (int cc = 0; cc < 16; ++cc) {
    int ci = chunk * 16 + cc;
    float v0 = bf2f(sv[ci * 66 + ul]);
    float v1 = bf2f(sv[ci * 66 + ul + 1]);
    float v2 = bf2f(sv[ci * 66 + ul + 2]);
    const float* wp = wph + ci * 13;
    a0 += v0 * wp[0] + v1 * wp[1];
    a1 += v0 * wp[3] + v1 * wp[4] + v2 * wp[5];
    a2 += v0 * wp[6] + v1 * wp[7] + v2 * wp[8];
    a3 += v1 * wp[10] + v2 * wp[11];
  }
  #pragma unroll
  for (int msk = 1; msk <= 2; msk <<= 1) {
    a0 += __shfl_xor(a0, msk);
    a1 += __shfl_xor(a1, msk);
    a2 += __shfl_xor(a2, msk);
    a3 += __shfl_xor(a3, msk);
  }
  if (chunk == 0) {
    float bv = bias[0];
    float4 r = make_float4(a0 + bv, a1 + bv, a2 + bv, a3 + bv);
    *(float4*)(out + (long)b * Tout + (long)(u0 + ul) * 4) = r;
  }
}

extern "C" void kernel_launch(void* const* d_in, const int* in_sizes, int n_in,
                              void* d_out, int out_size, void* d_ws, size_t ws_size,
                              hipStream_t stream) {
  const float* x     = (const float*)d_in[0];
  // d_in[1] = atoms: dead (sparse_code result unused by outputs)
  const float* ew    = (const float*)d_in[2];
  const float* eb    = (const float*)d_in[3];
  const float* w1    = (const float*)d_in[4];
  const float* b1    = (const float*)d_in[5];
  const float* g1    = (const float*)d_in[6];
  const float* be1   = (const float*)d_in[7];
  const float* w2    = (const float*)d_in[8];
  const float* b2    = (const float*)d_in[9];
  const float* g2    = (const float*)d_in[10];
  const float* be2   = (const float*)d_in[11];
  const float* w3    = (const float*)d_in[12];
  const float* b3    = (const float*)d_in[13];
  const float* up_w1 = (const float*)d_in[14];
  const float* up_b1 = (const float*)d_in[15];
  const float* bn_g1 = (const float*)d_in[16];
  const float* bn_b1 = (const float*)d_in[17];
  const float* up_w2 = (const float*)d_in[18];
  const float* up_b2 = (const float*)d_in[19];
  const float* bn_g2 = (const float*)d_in[20];
  const float* bn_b2 = (const float*)d_in[21];
  const float* up_w3 = (const float*)d_in[22];
  const float* up_b3 = (const float*)d_in[23];
  const float* bn_g3 = (const float*)d_in[24];
  const float* bn_b3 = (const float*)d_in[25];
  const float* up_w4 = (const float*)d_in[26];
  const float* up_b4 = (const float*)d_in[27];
  const float* bn_g4 = (const float*)d_in[28];
  const float* bn_b4 = (const float*)d_in[29];
  const float* up_w5 = (const float*)d_in[30];
  const float* up_b5 = (const float*)d_in[31];

  float* out = (float*)d_out;              // [0,131072) = y, [131072,135168) = ctx_out

  float* ws = (float*)d_ws;
  float* ctxb   = ws;                      // 4096
  float* gpart  = ctxb + 4096;             // 32768
  float* t2     = gpart + 32768;           // 4096
  float* statsp = t2 + 4096;               // 4096
  float* csum   = statsp + 4096;           // 2097152
  float* pbuf   = csum + 2097152;          // 4194304
  unsigned short* encbf = (unsigned short*)(pbuf + 4194304);  // 524288 u16
  unsigned short* o1 = encbf + 524288;     // 262144 u16
  unsigned short* o2 = o1 + 262144;        // 524288 u16
  unsigned short* o3 = o2 + 524288;        // 1048576 u16
  unsigned short* o4 = o3 + 1048576;       // 2097152 u16
  unsigned short* wbuf = o4 + 2097152;     // 5734400 u16

  // weight packing (templated, shifts only) + embed (LDS-staged MFMA) + fused ctx
  pack_all<<<2720, 256, 0, stream>>>(up_w1, up_w2, up_w3, up_w4, wbuf);
  embed_mfma<<<512, 256, 0, stream>>>(x, ew, eb, encbf, ctxb);

  // ctx MLP (split-K gemms, deterministic partial sums)
  gemm_p<<<dim3(32, 8), 256, 0, stream>>>(ctxb, w1, gpart);
  lnsum_kernel<<<4, 256, 0, stream>>>(gpart, b1, g1, be1, t2);
  gemm_p<<<dim3(32, 8), 256, 0, stream>>>(t2, w2, gpart);
  lnsum_kernel<<<4, 256, 0, stream>>>(gpart, b2, g2, be2, t2);
  gemm_p<<<dim3(32, 8), 256, 0, stream>>>(t2, w3, gpart);
  fin_kernel<<<16, 256, 0, stream>>>(gpart, b3, out + 131072);

  // ---- stage 1: (4,1024,128) -> (4,512,128), UPS=1, SK=8 ----
  conv_mfma<1, 8><<<512, 256, 22400, stream>>>(encbf, wbuf, pbuf, 1024, 512, 128);
  bnsum_kernel<<<dim3(512, 4), 256, 0, stream>>>(pbuf, statsp, csum, 512, 128, 8);
  bnapply_kernel<<<1024, 256, 0, stream>>>(csum, statsp, bn_g1, bn_b1, o1, 512, 7, 262144);

  // ---- stage 2: (4,512,128) -ph-> (4,256,512), SK=8 ----
  conv_ph<8><<<256, 256, 10560, stream>>>(o1, wbuf + 3670016, pbuf, 512, 256, 128);
  bnsum_kernel<<<dim3(256, 4), 256, 0, stream>>>(pbuf, statsp, csum, 256, 512, 8);
  bnapply_kernel<<<2048, 256, 0, stream>>>(csum, statsp, bn_g2, bn_b2, o2, 256, 9, 524288);

  // ---- stage 3: (4,256,512) -ph-> (4,128,2048), SK=4 ----
  conv_ph<4><<<256, 256, 10560, stream>>>(o2, wbuf + 5242880, pbuf, 256, 128, 512);
  bnsum_kernel<<<dim3(128, 4), 256, 0, stream>>>(pbuf, statsp, csum, 128, 2048, 4);
  bnapply_kernel<<<4096, 256, 0, stream>>>(csum, statsp, bn_g3, bn_b3, o3, 128, 11, 1048576);

  // ---- stage 4: (4,128,2048) -ph-> (4,64,8192), SK=2 ----
  conv_ph<2><<<256, 256, 10560, stream>>>(o3, wbuf + 5636096, pbuf, 128, 64, 2048);
  bnsum_kernel<<<dim3(64, 4), 256, 0, stream>>>(pbuf, statsp, csum, 64, 8192, 2);
  bnapply_kernel<<<8192, 256, 0, stream>>>(csum, statsp, bn_g4, bn_b4, o4, 64, 13, 2097152);

  // ---- stage 5: (4,64,8192) -ph-> (4,1,32768) ----
  conv5_kernel<<<dim3(128, 4), 256, 0, stream>>>(o4, up_w5, up_b5, out, 32768);
}

// Round 9
// 174.042 us; speedup vs baseline: 2.7385x; 1.0253x over previous
//
#include <hip/hip_runtime.h>
#include <hip/hip_bf16.h>

using sh8   = __attribute__((ext_vector_type(8))) short;
using sh4   = __attribute__((ext_vector_type(4))) short;
using f32x4 = __attribute__((ext_vector_type(4))) float;

#define DEV __device__ __forceinline__

DEV float leaky(float x) { return x >= 0.f ? x : 0.2f * x; }

DEV unsigned short f2bf(float f) {  // round-to-nearest-even f32 -> bf16 bits
  unsigned u = __float_as_uint(f);
  u += 0x7FFF + ((u >> 16) & 1);
  return (unsigned short)(u >> 16);
}
DEV float bf2f(unsigned short b) { return __uint_as_float(((unsigned)b) << 16); }

// ---------------- weight packing (templated: all dims pow2 -> shifts) ----------------
template<int Cout, int Cin>
DEV void pack7_body(const float* __restrict__ w, unsigned short* __restrict__ wp, int blk) {
  constexpr long plane = (long)(Cin >> 5) * Cout * 32;
  int tid = blk * 256 + threadIdx.x;
  if (tid >= Cout * Cin) return;
  int co = tid / Cin, ci = tid - co * Cin;
  const float* src = w + (long)tid * 7;
  unsigned short* dst = wp + ((long)(ci >> 5) * Cout + co) * 32 + (ci & 31);
  #pragma unroll
  for (int k = 0; k < 7; ++k) dst[k * plane] = f2bf(src[k]);
}
template<int Cout, int Cin>
DEV void packph_body(const float* __restrict__ w, unsigned short* __restrict__ wp, int blk) {
  constexpr long plane = (long)(Cin >> 5) * Cout * 32;
  int tid = blk * 256 + threadIdx.x;
  if (tid >= Cout * Cin) return;
  int co = tid / Cin, ci = tid - co * Cin;
  float wk[7];
  #pragma unroll
  for (int k = 0; k < 7; ++k) wk[k] = w[(long)tid * 7 + k];
  unsigned short* dst = wp + ((long)(ci >> 5) * Cout + co) * 32 + (ci & 31);
  #pragma unroll
  for (int p = 0; p < 4; ++p) {
    #pragma unroll
    for (int d = 0; d < 3; ++d) {
      float s = 0.f;
      #pragma unroll
      for (int k = 0; k < 7; ++k) if (((p + k + 1) >> 2) == d) s += wk[k];
      dst[(p * 3 + d) * plane] = f2bf(s);
    }
  }
}
__global__ __launch_bounds__(256)
void pack_all(const float* __restrict__ w1, const float* __restrict__ w2,
              const float* __restrict__ w3, const float* __restrict__ w4,
              unsigned short* __restrict__ wbuf) {
  int blk = blockIdx.x;
  if (blk < 2048)      pack7_body<512, 1024>(w1, wbuf, blk);
  else if (blk < 2560) packph_body<256, 512>(w2, wbuf + 3670016, blk - 2048);
  else if (blk < 2688) packph_body<128, 256>(w3, wbuf + 5242880, blk - 2560);
  else                 packph_body<64, 128>(w4, wbuf + 5636096, blk - 2688);
}

// ---------------- embed v5: MFMA GEMM, deep-pipelined LDS staging ----------------
// Block = one (b,band) = 128 rows, 2 phases of 64 rows sharing one LDS buffer.
// Staging: compile-time 8x8 batches (8 loads in flight) + 64-elem tail (row 63).
__global__ __launch_bounds__(256)
void embed_mfma(const float* __restrict__ x, const float* __restrict__ ew,
                const float* __restrict__ eb, unsigned short* __restrict__ encbf,
                float* __restrict__ ctx) {
  __shared__ unsigned short W16[257 * 16];   // [p][f], f>=8 zeroed
  __shared__ unsigned short sv[64 * 260];    // 64 rows x 257 bf16, stride 260
  __shared__ float ctxred[4][8];
  const int tid = threadIdx.x;
  const int bid = blockIdx.x;                // 512 groups
  const long rowbase = (long)bid * 128;
  const int b = bid >> 7, band = bid & 127;

  for (int i = tid; i < 257 * 16; i += 256) {
    int p = i >> 4, f = i & 15;
    W16[i] = (f < 8) ? f2bf(ew[p * 8 + f]) : (unsigned short)0;
  }
  {
    const float* src = x + rowbase * 257;
    #pragma unroll
    for (int u = 0; u < 8; ++u) {
      float tmp[8];
      #pragma unroll
      for (int v = 0; v < 8; ++v) tmp[v] = src[tid + (u * 8 + v) * 256];
      #pragma unroll
      for (int v = 0; v < 8; ++v) {
        int idx = tid + (u * 8 + v) * 256;
        int r = idx / 257, c = idx - r * 257;     // magic-mul, no div instr
        sv[r * 260 + c] = f2bf(tmp[v]);
      }
    }
    if (tid < 64) sv[63 * 260 + 193 + tid] = f2bf(src[16384 + tid]);
  }
  __syncthreads();

  const int w = tid >> 6, lane = tid & 63;
  const int m = lane & 15, g = lane >> 4;

  sh8 breg[8];
  #pragma unroll
  for (int kk = 0; kk < 8; ++kk) {
    #pragma unroll
    for (int j = 0; j < 8; ++j)
      breg[kk][j] = (short)W16[(kk * 32 + g * 8 + j) * 16 + m];
  }
  const float w256 = bf2f(W16[256 * 16 + m]);
  const float ebf = (m < 8) ? eb[m] : 0.f;

  float ctx_acc = 0.f;
  #pragma unroll
  for (int ph = 0; ph < 2; ++ph) {
    if (ph) {
      __syncthreads();                       // all phase-0 reads done
      const float* src = x + (rowbase + 64) * 257;
      #pragma unroll
      for (int u = 0; u < 8; ++u) {
        float tmp[8];
        #pragma unroll
        for (int v = 0; v < 8; ++v) tmp[v] = src[tid + (u * 8 + v) * 256];
        #pragma unroll
        for (int v = 0; v < 8; ++v) {
          int idx = tid + (u * 8 + v) * 256;
          int r = idx / 257, c = idx - r * 257;
          sv[r * 260 + c] = f2bf(tmp[v]);
        }
      }
      if (tid < 64) sv[63 * 260 + 193 + tid] = f2bf(src[16384 + tid]);
      __syncthreads();
    }
    f32x4 acc = {0.f, 0.f, 0.f, 0.f};
    const unsigned short* bp0 = sv + (w * 16 + m) * 260 + g * 8;
    #pragma unroll
    for (int kk = 0; kk < 8; ++kk) {
      sh4 lo = *(const sh4*)(bp0 + kk * 32);
      sh4 hi = *(const sh4*)(bp0 + kk * 32 + 4);
      sh8 afr;
      afr[0] = lo[0]; afr[1] = lo[1]; afr[2] = lo[2]; afr[3] = lo[3];
      afr[4] = hi[0]; afr[5] = hi[1]; afr[6] = hi[2]; afr[7] = hi[3];
      acc = __builtin_amdgcn_mfma_f32_16x16x32_bf16(afr, breg[kk], acc, 0, 0, 0);
    }
    const int t0 = ph * 64 + w * 16;
    unsigned short pk[4];
    #pragma unroll
    for (int r = 0; r < 4; ++r) {
      float xv = bf2f(sv[(w * 16 + g * 4 + r) * 260 + 256]);
      float e = acc[r] + xv * w256 + ebf;    // m>=8 lanes: exact 0
      pk[r] = f2bf(e);
      ctx_acc += e;
    }
    if (m < 8) {
      long o = ((long)b * 1024 + m * 128 + band) * 128 + t0 + g * 4;
      *(ushort4*)(encbf + o) = make_ushort4(pk[0], pk[1], pk[2], pk[3]);
    }
  }
  ctx_acc += __shfl_xor(ctx_acc, 16);
  ctx_acc += __shfl_xor(ctx_acc, 32);
  if (lane < 8) ctxred[w][lane] = ctx_acc;
  __syncthreads();
  if (tid < 8) {
    float sv2 = ctxred[0][tid] + ctxred[1][tid] + ctxred[2][tid] + ctxred[3][tid];
    ctx[(long)b * 1024 + tid * 128 + band] = sv2;
  }
}

// ---------------- split-K gemm: partial y = h(4,1024) @ w[k-chunk] ----------------
__global__ void gemm_p(const float* __restrict__ h, const float* __restrict__ w,
                       float* __restrict__ gpart) {
  __shared__ float hl[4][128];
  __shared__ float red[8][4][32];
  const int kc = blockIdx.y, jb = blockIdx.x, k0 = kc * 128;
  for (int i = threadIdx.x; i < 512; i += 256) {
    int bb = i >> 7, kk = i & 127;
    hl[bb][kk] = h[(bb << 10) + k0 + kk];
  }
  __syncthreads();
  const int jl = threadIdx.x & 31, kq = threadIdx.x >> 5;
  const int j = jb * 32 + jl;
  float a0 = 0, a1 = 0, a2 = 0, a3 = 0;
  const float* wp = w + (long)(k0 + kq * 16) * 1024 + j;
  #pragma unroll
  for (int k = 0; k < 16; ++k) {
    float wv = wp[(long)k * 1024];
    a0 += hl[0][kq * 16 + k] * wv;
    a1 += hl[1][kq * 16 + k] * wv;
    a2 += hl[2][kq * 16 + k] * wv;
    a3 += hl[3][kq * 16 + k] * wv;
  }
  red[kq][0][jl] = a0; red[kq][1][jl] = a1; red[kq][2][jl] = a2; red[kq][3][jl] = a3;
  __syncthreads();
  if (threadIdx.x < 128) {
    int bb = threadIdx.x >> 5, j2 = threadIdx.x & 31;
    float s = 0;
    #pragma unroll
    for (int q = 0; q < 8; ++q) s += red[q][bb][j2];
    gpart[((long)kc * 4 + bb) * 1024 + jb * 32 + j2] = s;
  }
}

// ---------------- sum split-K partials + bias + leaky + layernorm ----------------
__global__ void lnsum_kernel(const float* __restrict__ gpart, const float* __restrict__ bias,
                             const float* __restrict__ g, const float* __restrict__ be,
                             float* __restrict__ out) {
  int b = blockIdx.x;
  __shared__ float buf[1024];
  __shared__ float rs[4], rq[4];
  float s = 0, q = 0;
  #pragma unroll
  for (int i = 0; i < 4; ++i) {
    int j = threadIdx.x + i * 256;
    float v = bias[j];
    #pragma unroll
    for (int kc = 0; kc < 8; ++kc) v += gpart[((long)kc * 4 + b) * 1024 + j];
    v = leaky(v);
    buf[j] = v; s += v; q += v * v;
  }
  #pragma unroll
  for (int off = 32; off; off >>= 1) { s += __shfl_down(s, off); q += __shfl_down(q, off); }
  int wid = threadIdx.x >> 6, lane = threadIdx.x & 63;
  if (lane == 0) { rs[wid] = s; rq[wid] = q; }
  __syncthreads();
  float S = rs[0] + rs[1] + rs[2] + rs[3];
  float Q = rq[0] + rq[1] + rq[2] + rq[3];
  float mean = S * (1.f / 1024.f);
  float var = Q * (1.f / 1024.f) - mean * mean;
  float rstd = rsqrtf(var + 1e-5f);
  #pragma unroll
  for (int i = 0; i < 4; ++i) {
    int j = threadIdx.x + i * 256;
    out[b * 1024 + j] = (buf[j] - mean) * rstd * g[j] + be[j];
  }
}

// ---------------- final: ctx_out = sum partials + bias ----------------
__global__ void fin_kernel(const float* __restrict__ gpart, const float* __restrict__ bias,
                           float* __restrict__ out) {
  int i = blockIdx.x * 256 + threadIdx.x;   // 4096
  int b = i >> 10, j = i & 1023;
  float v = bias[j];
  #pragma unroll
  for (int kc = 0; kc < 8; ++kc) v += gpart[((long)kc * 4 + b) * 1024 + j];
  out[i] = v;
}

// ---------------- implicit-GEMM conv1d via MFMA bf16 (stage 1, UPS=1) ----------------
template<int UPS, int SPLITK>
__global__ __launch_bounds__(256, 2)
void conv_mfma(const unsigned short* __restrict__ act,
               const unsigned short* __restrict__ wpack,
               float* __restrict__ outp,
               int Cin, int Cout, int Tout) {
  constexpr int NC = (UPS == 1) ? 70 : 18;
  const int Tin = Tout / UPS;
  const int cpb = Cin / SPLITK;
  const int ncib = cpb >> 5;
  const int nCibTot = Cin >> 5;
  const int nco = Cout >> 6, nt = Tout >> 6;

  int bid = blockIdx.x;
  const int sk = bid % SPLITK; bid /= SPLITK;
  const int tt = bid % nt;  bid /= nt;
  const int cot = bid % nco; bid /= nco;
  const int b = bid;
  const int t0 = tt << 6, co0 = cot << 6;
  const int ci0 = sk * cpb;

  extern __shared__ unsigned short lin[];    // [ncib][NC][40]

  const unsigned short* actb = act + ((long)b * Cin + ci0) * Tin;
  const int u_base = (UPS == 1) ? (t0 - 3) : ((t0 >> 2) - 1);
  const int total = cpb * NC;
  for (int i = threadIdx.x; i < total; i += 256) {
    int ci = i / NC, ul = i - ci * NC;
    int u = u_base + ul;
    unsigned short v = 0;
    if (u >= 0 && u < Tin) v = actb[(long)ci * Tin + u];
    lin[((ci >> 5) * NC + ul) * 40 + (ci & 31)] = v;
  }
  __syncthreads();

  const int lane = threadIdx.x & 63, w = threadIdx.x >> 6;
  const int m = lane & 15, g = lane >> 4;

  int boff[28];
  #pragma unroll
  for (int s = 0; s < 4; ++s) {
    #pragma unroll
    for (int k = 0; k < 7; ++k) {
      int row = (UPS == 1) ? (s * 16 + m + k)
                           : (s * 4 + ((m + k + 9) >> 2) - 2);
      boff[s * 7 + k] = row * 40 + g * 8;
    }
  }

  const long wlane = ((long)(co0 + w * 16 + m) * 4 + g) * 8;

  f32x4 acc[4];
  #pragma unroll
  for (int s = 0; s < 4; ++s) { acc[s][0] = 0.f; acc[s][1] = 0.f; acc[s][2] = 0.f; acc[s][3] = 0.f; }

  for (int cib = 0; cib < ncib; ++cib) {
    const unsigned short* lb = lin + cib * (NC * 40);
    const int cg = (ci0 >> 5) + cib;
    sh8 a[7];
    #pragma unroll
    for (int k = 0; k < 7; ++k)
      a[k] = *(const sh8*)(wpack + (long)(k * nCibTot + cg) * Cout * 32 + wlane);
    #pragma unroll
    for (int k = 0; k < 7; ++k) {
      #pragma unroll
      for (int s = 0; s < 4; ++s) {
        sh8 bfr = *(const sh8*)(lb + boff[s * 7 + k]);
        acc[s] = __builtin_amdgcn_mfma_f32_16x16x32_bf16(a[k], bfr, acc[s], 0, 0, 0);
      }
    }
  }

  float* op = outp + (((long)sk * 4 + b) * Cout + (co0 + w * 16 + g * 4)) * (long)Tout + t0 + m;
  #pragma unroll
  for (int r = 0; r < 4; ++r) {
    #pragma unroll
    for (int s = 0; s < 4; ++s)
      op[(long)r * Tout + s * 16] = acc[s][r];
  }
}

// ---------------- phase-decomposed conv (UPS=4 stages): per-phase 3-tap GEMM ----------------
template<int SPLITK>
__global__ __launch_bounds__(256, 2)
void conv_ph(const unsigned short* __restrict__ act,
             const unsigned short* __restrict__ wpack,
             float* __restrict__ outp,
             int Cin, int Cout, int Tin) {
  const int Tout = Tin << 2;
  const int cpb = Cin / SPLITK;
  const int ncib = cpb >> 5;
  const int nCibTot = Cin >> 5;
  const int nco = Cout >> 6, ntu = Tin >> 6;

  int bid = blockIdx.x;
  const int sk = bid % SPLITK; bid /= SPLITK;
  const int tu = bid % ntu; bid /= ntu;
  const int cot = bid % nco; bid /= nco;
  const int b = bid;
  const int u0 = tu << 6, co0 = cot << 6;
  const int ci0 = sk * cpb;

  extern __shared__ unsigned short lin[];    // [ncib][66][40]

  const unsigned short* actb = act + ((long)b * Cin + ci0) * Tin;
  const int total = cpb * 66;
  for (int i = threadIdx.x; i < total; i += 256) {
    int ci = i / 66, r = i - ci * 66;
    int u = u0 - 1 + r;
    unsigned short v = 0;
    if (u >= 0 && u < Tin) v = actb[(long)ci * Tin + u];
    lin[((ci >> 5) * 66 + r) * 40 + (ci & 31)] = v;
  }
  __syncthreads();

  const int lane = threadIdx.x & 63, w = threadIdx.x >> 6;
  const int m = lane & 15, g = lane >> 4;

  int boff[4][3];
  #pragma unroll
  for (int s = 0; s < 4; ++s)
    #pragma unroll
    for (int d = 0; d < 3; ++d)
      boff[s][d] = (s * 16 + m + d) * 40 + g * 8;

  const long wlane = ((long)(co0 + w * 16 + m)) * 32 + g * 8;

  f32x4 acc[4][4];                           // [s][p]
  #pragma unroll
  for (int s = 0; s < 4; ++s)
    #pragma unroll
    for (int p = 0; p < 4; ++p) { acc[s][p][0] = 0.f; acc[s][p][1] = 0.f; acc[s][p][2] = 0.f; acc[s][p][3] = 0.f; }

  for (int cib = 0; cib < ncib; ++cib) {
    const unsigned short* lb = lin + cib * (66 * 40);
    const int cg = (ci0 >> 5) + cib;
    sh8 a[12];
    #pragma unroll
    for (int pd = 0; pd < 12; ++pd)
      a[pd] = *(const sh8*)(wpack + ((long)(pd * nCibTot + cg) * Cout) * 32 + wlane);
    #pragma unroll
    for (int s = 0; s < 4; ++s) {
      sh8 b0 = *(const sh8*)(lb + boff[s][0]);
      sh8 b1 = *(const sh8*)(lb + boff[s][1]);
      sh8 b2 = *(const sh8*)(lb + boff[s][2]);
      acc[s][0] = __builtin_amdgcn_mfma_f32_16x16x32_bf16(a[0],  b0, acc[s][0], 0, 0, 0);
      acc[s][0] = __builtin_amdgcn_mfma_f32_16x16x32_bf16(a[1],  b1, acc[s][0], 0, 0, 0);
      acc[s][1] = __builtin_amdgcn_mfma_f32_16x16x32_bf16(a[3],  b0, acc[s][1], 0, 0, 0);
      acc[s][1] = __builtin_amdgcn_mfma_f32_16x16x32_bf16(a[4],  b1, acc[s][1], 0, 0, 0);
      acc[s][1] = __builtin_amdgcn_mfma_f32_16x16x32_bf16(a[5],  b2, acc[s][1], 0, 0, 0);
      acc[s][2] = __builtin_amdgcn_mfma_f32_16x16x32_bf16(a[6],  b0, acc[s][2], 0, 0, 0);
      acc[s][2] = __builtin_amdgcn_mfma_f32_16x16x32_bf16(a[7],  b1, acc[s][2], 0, 0, 0);
      acc[s][2] = __builtin_amdgcn_mfma_f32_16x16x32_bf16(a[8],  b2, acc[s][2], 0, 0, 0);
      acc[s][3] = __builtin_amdgcn_mfma_f32_16x16x32_bf16(a[10], b1, acc[s][3], 0, 0, 0);
      acc[s][3] = __builtin_amdgcn_mfma_f32_16x16x32_bf16(a[11], b2, acc[s][3], 0, 0, 0);
    }
  }

  float* op = outp + (((long)sk * 4 + b) * Cout + (co0 + w * 16 + g * 4)) * (long)Tout;
  #pragma unroll
  for (int r = 0; r < 4; ++r) {
    #pragma unroll
    for (int s = 0; s < 4; ++s) {
      float4 v4 = make_float4(acc[s][0][r], acc[s][1][r], acc[s][2][r], acc[s][3][r]);
      *(float4*)(op + (long)r * Tout + ((u0 + s * 16 + m) << 2)) = v4;
    }
  }
}

// ---------------- bn stats: sum split-K (write csum) + per-(c,b) partial stats ----------------
__global__ void bnsum_kernel(const float* __restrict__ p, float* __restrict__ sp,
                             float* __restrict__ csum, int C, int T, int SK) {
  int c = blockIdx.x, b = blockIdx.y;
  long stride = (long)4 * C * T;
  const float* r = p + ((long)b * C + c) * T;
  float* cw = csum + ((long)b * C + c) * T;
  float s = 0, q = 0;
  for (int t = threadIdx.x; t < T; t += 256) {
    float v = r[t];
    for (int k = 1; k < SK; ++k) v += r[t + k * stride];
    cw[t] = v;
    s += v; q += v * v;
  }
  #pragma unroll
  for (int off = 32; off; off >>= 1) { s += __shfl_down(s, off); q += __shfl_down(q, off); }
  __shared__ float rs[4], rq[4];
  int wid = threadIdx.x >> 6, lane = threadIdx.x & 63;
  if (lane == 0) { rs[wid] = s; rq[wid] = q; }
  __syncthreads();
  if (threadIdx.x == 0) {
    sp[c * 4 + b] = rs[0] + rs[1] + rs[2] + rs[3];
    sp[C * 4 + c * 4 + b] = rq[0] + rq[1] + rq[2] + rq[3];
  }
}

// ---------------- bn finalize + leaky, emit bf16 (reads csum) ----------------
__global__ void bnapply_kernel(const float* __restrict__ csum, const float* __restrict__ sp,
                               const float* __restrict__ g, const float* __restrict__ be,
                               unsigned short* __restrict__ obf,
                               int C, int tshift, int total) {
  int i = blockIdx.x * 256 + threadIdx.x;
  if (i >= total) return;
  float v = csum[i];
  int c = (i >> tshift) & (C - 1);
  float s = sp[c * 4] + sp[c * 4 + 1] + sp[c * 4 + 2] + sp[c * 4 + 3];
  float q = sp[C * 4 + c * 4] + sp[C * 4 + c * 4 + 1] + sp[C * 4 + c * 4 + 2] + sp[C * 4 + c * 4 + 3];
  float n = (float)(4 << tshift);
  float mean = s / n;
  float var = q / n - mean * mean;
  float sc = g[c] * rsqrtf(var + 1e-5f);
  float sh = be[c] - mean * sc;
  obf[i] = f2bf(leaky(v * sc + sh));
}

// ---------------- final conv: phase-decomposed 3-tap ----------------
__global__ __launch_bounds__(256)
void conv5_kernel(const unsigned short* __restrict__ in, const float* __restrict__ wgt,
                  const float* __restrict__ bias, float* __restrict__ out, int Tout) {
  __shared__ unsigned short sv[64 * 66];
  __shared__ float wph[64 * 13];

  const int b = blockIdx.y;
  const int u0 = blockIdx.x * 64;
  const int Tin = Tout >> 2;
  const int tid = threadIdx.x;

  {
    int ci = tid >> 2, pp = tid & 3;
    float s0 = 0, s1 = 0, s2 = 0;
    #pragma unroll
    for (int k = 0; k < 7; ++k) {
      int d = (pp - 3 + k + 4) >> 2;
      float wv = wgt[ci * 7 + k];
      if (d == 0) s0 += wv; else if (d == 1) s1 += wv; else s2 += wv;
    }
    wph[ci * 13 + pp * 3 + 0] = s0;
    wph[ci * 13 + pp * 3 + 1] = s1;
    wph[ci * 13 + pp * 3 + 2] = s2;
  }

  const unsigned short* inb = in + (long)b * 64 * Tin;
  for (int i = tid; i < 64 * 66; i += 256) {
    int ci = i / 66, uu = i - ci * 66;
    int u = u0 - 1 + uu;
    unsigned short v = 0;
    if (u >= 0 && u < Tin) v = inb[(long)ci * Tin + u];
    sv[ci * 66 + uu] = v;
  }
  __syncthreads();

  const int ul = tid >> 2;
  const int chunk = tid & 3;
  float a0 = 0, a1 = 0, a2 = 0, a3 = 0;
  #pragma unroll
  for (int cc = 0; cc < 16; ++cc) {
    int ci = chunk * 16 + cc;
    float v0 = bf2f(sv[ci * 66 + ul]);
    float v1 = bf2f(sv[ci * 66 + ul + 1]);
    float v2 = bf2f(sv[ci * 66 + ul + 2]);
    const float* wp = wph + ci * 13;
    a0 += v0 * wp[0] + v1 * wp[1];
    a1 += v0 * wp[3] + v1 * wp[4] + v2 * wp[5];
    a2 += v0 * wp[6] + v1 * wp[7] + v2 * wp[8];
    a3 += v1 * wp[10] + v2 * wp[11];
  }
  #pragma unroll
  for (int msk = 1; msk <= 2; msk <<= 1) {
    a0 += __shfl_xor(a0, msk);
    a1 += __shfl_xor(a1, msk);
    a2 += __shfl_xor(a2, msk);
    a3 += __shfl_xor(a3, msk);
  }
  if (chunk == 0) {
    float bv = bias[0];
    float4 r = make_float4(a0 + bv, a1 + bv, a2 + bv, a3 + bv);
    *(float4*)(out + (long)b * Tout + (long)(u0 + ul) * 4) = r;
  }
}

extern "C" void kernel_launch(void* const* d_in, const int* in_sizes, int n_in,
                              void* d_out, int out_size, void* d_ws, size_t ws_size,
                              hipStream_t stream) {
  const float* x     = (const float*)d_in[0];
  // d_in[1] = atoms: dead (sparse_code result unused by outputs)
  const float* ew    = (const float*)d_in[2];
  const float* eb    = (const float*)d_in[3];
  const float* w1    = (const float*)d_in[4];
  const float* b1    = (const float*)d_in[5];
  const float* g1    = (const float*)d_in[6];
  const float* be1   = (const float*)d_in[7];
  const float* w2    = (const float*)d_in[8];
  const float* b2    = (const float*)d_in[9];
  const float* g2    = (const float*)d_in[10];
  const float* be2   = (const float*)d_in[11];
  const float* w3    = (const float*)d_in[12];
  const float* b3    = (const float*)d_in[13];
  const float* up_w1 = (const float*)d_in[14];
  const float* up_b1 = (const float*)d_in[15];
  const float* bn_g1 = (const float*)d_in[16];
  const float* bn_b1 = (const float*)d_in[17];
  const float* up_w2 = (const float*)d_in[18];
  const float* up_b2 = (const float*)d_in[19];
  const float* bn_g2 = (const float*)d_in[20];
  const float* bn_b2 = (const float*)d_in[21];
  const float* up_w3 = (const float*)d_in[22];
  const float* up_b3 = (const float*)d_in[23];
  const float* bn_g3 = (const float*)d_in[24];
  const float* bn_b3 = (const float*)d_in[25];
  const float* up_w4 = (const float*)d_in[26];
  const float* up_b4 = (const float*)d_in[27];
  const float* bn_g4 = (const float*)d_in[28];
  const float* bn_b4 = (const float*)d_in[29];
  const float* up_w5 = (const float*)d_in[30];
  const float* up_b5 = (const float*)d_in[31];

  float* out = (float*)d_out;              // [0,131072) = y, [131072,135168) = ctx_out

  float* ws = (float*)d_ws;
  float* ctxb   = ws;                      // 4096
  float* gpart  = ctxb + 4096;             // 32768
  float* t2     = gpart + 32768;           // 4096
  float* statsp = t2 + 4096;               // 4096
  float* csum   = statsp + 4096;           // 2097152
  float* pbuf   = csum + 2097152;          // 4194304
  unsigned short* encbf = (unsigned short*)(pbuf + 4194304);  // 524288 u16
  unsigned short* o1 = encbf + 524288;     // 262144 u16
  unsigned short* o2 = o1 + 262144;        // 524288 u16
  unsigned short* o3 = o2 + 524288;        // 1048576 u16
  unsigned short* o4 = o3 + 1048576;       // 2097152 u16
  unsigned short* wbuf = o4 + 2097152;     // 5734400 u16

  // weight packing + embed (deep-pipelined LDS staging) + fused ctx
  pack_all<<<2720, 256, 0, stream>>>(up_w1, up_w2, up_w3, up_w4, wbuf);
  embed_mfma<<<512, 256, 0, stream>>>(x, ew, eb, encbf, ctxb);

  // ctx MLP (split-K gemms, deterministic partial sums)
  gemm_p<<<dim3(32, 8), 256, 0, stream>>>(ctxb, w1, gpart);
  lnsum_kernel<<<4, 256, 0, stream>>>(gpart, b1, g1, be1, t2);
  gemm_p<<<dim3(32, 8), 256, 0, stream>>>(t2, w2, gpart);
  lnsum_kernel<<<4, 256, 0, stream>>>(gpart, b2, g2, be2, t2);
  gemm_p<<<dim3(32, 8), 256, 0, stream>>>(t2, w3, gpart);
  fin_kernel<<<16, 256, 0, stream>>>(gpart, b3, out + 131072);

  // ---- stage 1: (4,1024,128) -> (4,512,128), UPS=1, SK=8 ----
  conv_mfma<1, 8><<<512, 256, 22400, stream>>>(encbf, wbuf, pbuf, 1024, 512, 128);
  bnsum_kernel<<<dim3(512, 4), 256, 0, stream>>>(pbuf, statsp, csum, 512, 128, 8);
  bnapply_kernel<<<1024, 256, 0, stream>>>(csum, statsp, bn_g1, bn_b1, o1, 512, 7, 262144);

  // ---- stage 2: (4,512,128) -ph-> (4,256,512), SK=8 ----
  conv_ph<8><<<256, 256, 10560, stream>>>(o1, wbuf + 3670016, pbuf, 512, 256, 128);
  bnsum_kernel<<<dim3(256, 4), 256, 0, stream>>>(pbuf, statsp, csum, 256, 512, 8);
  bnapply_kernel<<<2048, 256, 0, stream>>>(csum, statsp, bn_g2, bn_b2, o2, 256, 9, 524288);

  // ---- stage 3: (4,256,512) -ph-> (4,128,2048), SK=4 ----
  conv_ph<4><<<256, 256, 10560, stream>>>(o2, wbuf + 5242880, pbuf, 256, 128, 512);
  bnsum_kernel<<<dim3(128, 4), 256, 0, stream>>>(pbuf, statsp, csum, 128, 2048, 4);
  bnapply_kernel<<<4096, 256, 0, stream>>>(csum, statsp, bn_g3, bn_b3, o3, 128, 11, 1048576);

  // ---- stage 4: (4,128,2048) -ph-> (4,64,8192), SK=2 ----
  conv_ph<2><<<256, 256, 10560, stream>>>(o3, wbuf + 5636096, pbuf, 128, 64, 2048);
  bnsum_kernel<<<dim3(64, 4), 256, 0, stream>>>(pbuf, statsp, csum, 64, 8192, 2);
  bnapply_kernel<<<8192, 256, 0, stream>>>(csum, statsp, bn_g4, bn_b4, o4, 64, 13, 2097152);

  // ---- stage 5: (4,64,8192) -ph-> (4,1,32768) ----
  conv5_kernel<<<dim3(128, 4), 256, 0, stream>>>(o4, up_w5, up_b5, out, 32768);
}

// Round 10
// 167.100 us; speedup vs baseline: 2.8522x; 1.0415x over previous
//
#include <hip/hip_runtime.h>
#include <hip/hip_bf16.h>

using sh8   = __attribute__((ext_vector_type(8))) short;
using sh4   = __attribute__((ext_vector_type(4))) short;
using f32x4 = __attribute__((ext_vector_type(4))) float;

#define DEV __device__ __forceinline__

DEV float leaky(float x) { return x >= 0.f ? x : 0.2f * x; }

DEV unsigned short f2bf(float f) {  // round-to-nearest-even f32 -> bf16 bits
  unsigned u = __float_as_uint(f);
  u += 0x7FFF + ((u >> 16) & 1);
  return (unsigned short)(u >> 16);
}
DEV float bf2f(unsigned short b) { return __uint_as_float(((unsigned)b) << 16); }

// ---------------- weight packing (templated: all dims pow2 -> shifts) ----------------
template<int Cout, int Cin>
DEV void pack7_body(const float* __restrict__ w, unsigned short* __restrict__ wp, int blk) {
  constexpr long plane = (long)(Cin >> 5) * Cout * 32;
  int tid = blk * 256 + threadIdx.x;
  if (tid >= Cout * Cin) return;
  int co = tid / Cin, ci = tid - co * Cin;
  const float* src = w + (long)tid * 7;
  unsigned short* dst = wp + ((long)(ci >> 5) * Cout + co) * 32 + (ci & 31);
  #pragma unroll
  for (int k = 0; k < 7; ++k) dst[k * plane] = f2bf(src[k]);
}
template<int Cout, int Cin>
DEV void packph_body(const float* __restrict__ w, unsigned short* __restrict__ wp, int blk) {
  constexpr long plane = (long)(Cin >> 5) * Cout * 32;
  int tid = blk * 256 + threadIdx.x;
  if (tid >= Cout * Cin) return;
  int co = tid / Cin, ci = tid - co * Cin;
  float wk[7];
  #pragma unroll
  for (int k = 0; k < 7; ++k) wk[k] = w[(long)tid * 7 + k];
  unsigned short* dst = wp + ((long)(ci >> 5) * Cout + co) * 32 + (ci & 31);
  #pragma unroll
  for (int p = 0; p < 4; ++p) {
    #pragma unroll
    for (int d = 0; d < 3; ++d) {
      float s = 0.f;
      #pragma unroll
      for (int k = 0; k < 7; ++k) if (((p + k + 1) >> 2) == d) s += wk[k];
      dst[(p * 3 + d) * plane] = f2bf(s);
    }
  }
}
__global__ __launch_bounds__(256)
void pack_all(const float* __restrict__ w1, const float* __restrict__ w2,
              const float* __restrict__ w3, const float* __restrict__ w4,
              unsigned short* __restrict__ wbuf) {
  int blk = blockIdx.x;
  if (blk < 2048)      pack7_body<512, 1024>(w1, wbuf, blk);
  else if (blk < 2560) packph_body<256, 512>(w2, wbuf + 3670016, blk - 2048);
  else if (blk < 2688) packph_body<128, 256>(w3, wbuf + 5242880, blk - 2560);
  else                 packph_body<64, 128>(w4, wbuf + 5636096, blk - 2688);
}

// ---------------- embed: MFMA GEMM, deep-pipelined LDS staging, fused ctx ----------------
__global__ __launch_bounds__(256)
void embed_mfma(const float* __restrict__ x, const float* __restrict__ ew,
                const float* __restrict__ eb, unsigned short* __restrict__ encbf,
                float* __restrict__ ctx) {
  __shared__ unsigned short W16[257 * 16];   // [p][f], f>=8 zeroed
  __shared__ unsigned short sv[64 * 260];    // 64 rows x 257 bf16, stride 260
  __shared__ float ctxred[4][8];
  const int tid = threadIdx.x;
  const int bid = blockIdx.x;                // 512 groups
  const long rowbase = (long)bid * 128;
  const int b = bid >> 7, band = bid & 127;

  for (int i = tid; i < 257 * 16; i += 256) {
    int p = i >> 4, f = i & 15;
    W16[i] = (f < 8) ? f2bf(ew[p * 8 + f]) : (unsigned short)0;
  }
  {
    const float* src = x + rowbase * 257;
    #pragma unroll
    for (int u = 0; u < 8; ++u) {
      float tmp[8];
      #pragma unroll
      for (int v = 0; v < 8; ++v) tmp[v] = src[tid + (u * 8 + v) * 256];
      #pragma unroll
      for (int v = 0; v < 8; ++v) {
        int idx = tid + (u * 8 + v) * 256;
        int r = idx / 257, c = idx - r * 257;
        sv[r * 260 + c] = f2bf(tmp[v]);
      }
    }
    if (tid < 64) sv[63 * 260 + 193 + tid] = f2bf(src[16384 + tid]);
  }
  __syncthreads();

  const int w = tid >> 6, lane = tid & 63;
  const int m = lane & 15, g = lane >> 4;

  sh8 breg[8];
  #pragma unroll
  for (int kk = 0; kk < 8; ++kk) {
    #pragma unroll
    for (int j = 0; j < 8; ++j)
      breg[kk][j] = (short)W16[(kk * 32 + g * 8 + j) * 16 + m];
  }
  const float w256 = bf2f(W16[256 * 16 + m]);
  const float ebf = (m < 8) ? eb[m] : 0.f;

  float ctx_acc = 0.f;
  #pragma unroll
  for (int ph = 0; ph < 2; ++ph) {
    if (ph) {
      __syncthreads();
      const float* src = x + (rowbase + 64) * 257;
      #pragma unroll
      for (int u = 0; u < 8; ++u) {
        float tmp[8];
        #pragma unroll
        for (int v = 0; v < 8; ++v) tmp[v] = src[tid + (u * 8 + v) * 256];
        #pragma unroll
        for (int v = 0; v < 8; ++v) {
          int idx = tid + (u * 8 + v) * 256;
          int r = idx / 257, c = idx - r * 257;
          sv[r * 260 + c] = f2bf(tmp[v]);
        }
      }
      if (tid < 64) sv[63 * 260 + 193 + tid] = f2bf(src[16384 + tid]);
      __syncthreads();
    }
    f32x4 acc = {0.f, 0.f, 0.f, 0.f};
    const unsigned short* bp0 = sv + (w * 16 + m) * 260 + g * 8;
    #pragma unroll
    for (int kk = 0; kk < 8; ++kk) {
      sh4 lo = *(const sh4*)(bp0 + kk * 32);
      sh4 hi = *(const sh4*)(bp0 + kk * 32 + 4);
      sh8 afr;
      afr[0] = lo[0]; afr[1] = lo[1]; afr[2] = lo[2]; afr[3] = lo[3];
      afr[4] = hi[0]; afr[5] = hi[1]; afr[6] = hi[2]; afr[7] = hi[3];
      acc = __builtin_amdgcn_mfma_f32_16x16x32_bf16(afr, breg[kk], acc, 0, 0, 0);
    }
    const int t0 = ph * 64 + w * 16;
    unsigned short pk[4];
    #pragma unroll
    for (int r = 0; r < 4; ++r) {
      float xv = bf2f(sv[(w * 16 + g * 4 + r) * 260 + 256]);
      float e = acc[r] + xv * w256 + ebf;    // m>=8 lanes: exact 0
      pk[r] = f2bf(e);
      ctx_acc += e;
    }
    if (m < 8) {
      long o = ((long)b * 1024 + m * 128 + band) * 128 + t0 + g * 4;
      *(ushort4*)(encbf + o) = make_ushort4(pk[0], pk[1], pk[2], pk[3]);
    }
  }
  ctx_acc += __shfl_xor(ctx_acc, 16);
  ctx_acc += __shfl_xor(ctx_acc, 32);
  if (lane < 8) ctxred[w][lane] = ctx_acc;
  __syncthreads();
  if (tid < 8) {
    float sv2 = ctxred[0][tid] + ctxred[1][tid] + ctxred[2][tid] + ctxred[3][tid];
    ctx[(long)b * 1024 + tid * 128 + band] = sv2;
  }
}

// ---------------- split-K gemm: partial y = h(4,1024) @ w[k-chunk] ----------------
__global__ void gemm_p(const float* __restrict__ h, const float* __restrict__ w,
                       float* __restrict__ gpart) {
  __shared__ float hl[4][128];
  __shared__ float red[8][4][32];
  const int kc = blockIdx.y, jb = blockIdx.x, k0 = kc * 128;
  for (int i = threadIdx.x; i < 512; i += 256) {
    int bb = i >> 7, kk = i & 127;
    hl[bb][kk] = h[(bb << 10) + k0 + kk];
  }
  __syncthreads();
  const int jl = threadIdx.x & 31, kq = threadIdx.x >> 5;
  const int j = jb * 32 + jl;
  float a0 = 0, a1 = 0, a2 = 0, a3 = 0;
  const float* wp = w + (long)(k0 + kq * 16) * 1024 + j;
  #pragma unroll
  for (int k = 0; k < 16; ++k) {
    float wv = wp[(long)k * 1024];
    a0 += hl[0][kq * 16 + k] * wv;
    a1 += hl[1][kq * 16 + k] * wv;
    a2 += hl[2][kq * 16 + k] * wv;
    a3 += hl[3][kq * 16 + k] * wv;
  }
  red[kq][0][jl] = a0; red[kq][1][jl] = a1; red[kq][2][jl] = a2; red[kq][3][jl] = a3;
  __syncthreads();
  if (threadIdx.x < 128) {
    int bb = threadIdx.x >> 5, j2 = threadIdx.x & 31;
    float s = 0;
    #pragma unroll
    for (int q = 0; q < 8; ++q) s += red[q][bb][j2];
    gpart[((long)kc * 4 + bb) * 1024 + jb * 32 + j2] = s;
  }
}

// ---------------- sum split-K partials + bias + leaky + layernorm ----------------
__global__ void lnsum_kernel(const float* __restrict__ gpart, const float* __restrict__ bias,
                             const float* __restrict__ g, const float* __restrict__ be,
                             float* __restrict__ out) {
  int b = blockIdx.x;
  __shared__ float buf[1024];
  __shared__ float rs[4], rq[4];
  float s = 0, q = 0;
  #pragma unroll
  for (int i = 0; i < 4; ++i) {
    int j = threadIdx.x + i * 256;
    float v = bias[j];
    #pragma unroll
    for (int kc = 0; kc < 8; ++kc) v += gpart[((long)kc * 4 + b) * 1024 + j];
    v = leaky(v);
    buf[j] = v; s += v; q += v * v;
  }
  #pragma unroll
  for (int off = 32; off; off >>= 1) { s += __shfl_down(s, off); q += __shfl_down(q, off); }
  int wid = threadIdx.x >> 6, lane = threadIdx.x & 63;
  if (lane == 0) { rs[wid] = s; rq[wid] = q; }
  __syncthreads();
  float S = rs[0] + rs[1] + rs[2] + rs[3];
  float Q = rq[0] + rq[1] + rq[2] + rq[3];
  float mean = S * (1.f / 1024.f);
  float var = Q * (1.f / 1024.f) - mean * mean;
  float rstd = rsqrtf(var + 1e-5f);
  #pragma unroll
  for (int i = 0; i < 4; ++i) {
    int j = threadIdx.x + i * 256;
    out[b * 1024 + j] = (buf[j] - mean) * rstd * g[j] + be[j];
  }
}

// ---------------- final: ctx_out = sum partials + bias ----------------
__global__ void fin_kernel(const float* __restrict__ gpart, const float* __restrict__ bias,
                           float* __restrict__ out) {
  int i = blockIdx.x * 256 + threadIdx.x;   // 4096
  int b = i >> 10, j = i & 1023;
  float v = bias[j];
  #pragma unroll
  for (int kc = 0; kc < 8; ++kc) v += gpart[((long)kc * 4 + b) * 1024 + j];
  out[i] = v;
}

// ---------------- implicit-GEMM conv1d via MFMA bf16 (stage 1, UPS=1) ----------------
template<int UPS, int SPLITK>
__global__ __launch_bounds__(256, 2)
void conv_mfma(const unsigned short* __restrict__ act,
               const unsigned short* __restrict__ wpack,
               float* __restrict__ outp,
               int Cin, int Cout, int Tout) {
  constexpr int NC = (UPS == 1) ? 70 : 18;
  const int Tin = Tout / UPS;
  const int cpb = Cin / SPLITK;
  const int ncib = cpb >> 5;
  const int nCibTot = Cin >> 5;
  const int nco = Cout >> 6, nt = Tout >> 6;

  int bid = blockIdx.x;
  const int sk = bid % SPLITK; bid /= SPLITK;
  const int tt = bid % nt;  bid /= nt;
  const int cot = bid % nco; bid /= nco;
  const int b = bid;
  const int t0 = tt << 6, co0 = cot << 6;
  const int ci0 = sk * cpb;

  extern __shared__ unsigned short lin[];    // [ncib][NC][40]

  const unsigned short* actb = act + ((long)b * Cin + ci0) * Tin;
  const int u_base = (UPS == 1) ? (t0 - 3) : ((t0 >> 2) - 1);
  const int total = cpb * NC;
  for (int i = threadIdx.x; i < total; i += 256) {
    int ci = i / NC, ul = i - ci * NC;
    int u = u_base + ul;
    unsigned short v = 0;
    if (u >= 0 && u < Tin) v = actb[(long)ci * Tin + u];
    lin[((ci >> 5) * NC + ul) * 40 + (ci & 31)] = v;
  }
  __syncthreads();

  const int lane = threadIdx.x & 63, w = threadIdx.x >> 6;
  const int m = lane & 15, g = lane >> 4;

  int boff[28];
  #pragma unroll
  for (int s = 0; s < 4; ++s) {
    #pragma unroll
    for (int k = 0; k < 7; ++k) {
      int row = (UPS == 1) ? (s * 16 + m + k)
                           : (s * 4 + ((m + k + 9) >> 2) - 2);
      boff[s * 7 + k] = row * 40 + g * 8;
    }
  }

  const long wlane = ((long)(co0 + w * 16 + m) * 4 + g) * 8;

  f32x4 acc[4];
  #pragma unroll
  for (int s = 0; s < 4; ++s) { acc[s][0] = 0.f; acc[s][1] = 0.f; acc[s][2] = 0.f; acc[s][3] = 0.f; }

  for (int cib = 0; cib < ncib; ++cib) {
    const unsigned short* lb = lin + cib * (NC * 40);
    const int cg = (ci0 >> 5) + cib;
    sh8 a[7];
    #pragma unroll
    for (int k = 0; k < 7; ++k)
      a[k] = *(const sh8*)(wpack + (long)(k * nCibTot + cg) * Cout * 32 + wlane);
    #pragma unroll
    for (int k = 0; k < 7; ++k) {
      #pragma unroll
      for (int s = 0; s < 4; ++s) {
        sh8 bfr = *(const sh8*)(lb + boff[s * 7 + k]);
        acc[s] = __builtin_amdgcn_mfma_f32_16x16x32_bf16(a[k], bfr, acc[s], 0, 0, 0);
      }
    }
  }

  float* op = outp + (((long)sk * 4 + b) * Cout + (co0 + w * 16 + g * 4)) * (long)Tout + t0 + m;
  #pragma unroll
  for (int r = 0; r < 4; ++r) {
    #pragma unroll
    for (int s = 0; s < 4; ++s)
      op[(long)r * Tout + s * 16] = acc[s][r];
  }
}

// ---------------- phase-decomposed conv with FUSED bn-apply in staging ----------------
// Reads f32 csum (prev stage's split-K-summed conv out) + statsp; applies
// per-channel affine+leaky while staging to LDS bf16. OOB columns stage 0 (= conv pad).
template<int SPLITK>
__global__ __launch_bounds__(256, 2)
void conv_ph(const float* __restrict__ csum_in, const float* __restrict__ sp,
             const float* __restrict__ g, const float* __restrict__ be,
             const unsigned short* __restrict__ wpack,
             float* __restrict__ outp,
             int Cin, int Cout, int Tin) {
  const int Tout = Tin << 2;
  const int cpb = Cin / SPLITK;
  const int ncib = cpb >> 5;
  const int nCibTot = Cin >> 5;
  const int nco = Cout >> 6, ntu = Tin >> 6;

  int bid = blockIdx.x;
  const int sk = bid % SPLITK; bid /= SPLITK;
  const int tu = bid % ntu; bid /= ntu;
  const int cot = bid % nco; bid /= nco;
  const int b = bid;
  const int u0 = tu << 6, co0 = cot << 6;
  const int ci0 = sk * cpb;

  extern __shared__ unsigned short lin[];    // [ncib][66][40]
  __shared__ float ssc[64], ssh[64];

  if (threadIdx.x < cpb) {
    int c = ci0 + threadIdx.x;
    float S = sp[c * 4] + sp[c * 4 + 1] + sp[c * 4 + 2] + sp[c * 4 + 3];
    float Q = sp[Cin * 4 + c * 4] + sp[Cin * 4 + c * 4 + 1] + sp[Cin * 4 + c * 4 + 2] + sp[Cin * 4 + c * 4 + 3];
    float n = 4.f * (float)Tin;
    float mean = S / n;
    float var = Q / n - mean * mean;
    float sc = g[c] * rsqrtf(var + 1e-5f);
    ssc[threadIdx.x] = sc;
    ssh[threadIdx.x] = be[c] - mean * sc;
  }
  __syncthreads();

  const float* csb = csum_in + ((long)b * Cin + ci0) * Tin;
  const int total = cpb * 66;
  for (int i = threadIdx.x; i < total; i += 256) {
    int ci = i / 66, r = i - ci * 66;
    int u = u0 - 1 + r;
    unsigned short v = 0;
    if (u >= 0 && u < Tin) {
      float t = csb[(long)ci * Tin + u];
      v = f2bf(leaky(t * ssc[ci] + ssh[ci]));
    }
    lin[((ci >> 5) * 66 + r) * 40 + (ci & 31)] = v;
  }
  __syncthreads();

  const int lane = threadIdx.x & 63, w = threadIdx.x >> 6;
  const int m = lane & 15, g2 = lane >> 4;

  int boff[4][3];
  #pragma unroll
  for (int s = 0; s < 4; ++s)
    #pragma unroll
    for (int d = 0; d < 3; ++d)
      boff[s][d] = (s * 16 + m + d) * 40 + g2 * 8;

  const long wlane = ((long)(co0 + w * 16 + m)) * 32 + g2 * 8;

  f32x4 acc[4][4];                           // [s][p]
  #pragma unroll
  for (int s = 0; s < 4; ++s)
    #pragma unroll
    for (int p = 0; p < 4; ++p) { acc[s][p][0] = 0.f; acc[s][p][1] = 0.f; acc[s][p][2] = 0.f; acc[s][p][3] = 0.f; }

  for (int cib = 0; cib < ncib; ++cib) {
    const unsigned short* lb = lin + cib * (66 * 40);
    const int cg = (ci0 >> 5) + cib;
    sh8 a[12];
    #pragma unroll
    for (int pd = 0; pd < 12; ++pd)
      a[pd] = *(const sh8*)(wpack + ((long)(pd * nCibTot + cg) * Cout) * 32 + wlane);
    #pragma unroll
    for (int s = 0; s < 4; ++s) {
      sh8 b0 = *(const sh8*)(lb + boff[s][0]);
      sh8 b1 = *(const sh8*)(lb + boff[s][1]);
      sh8 b2 = *(const sh8*)(lb + boff[s][2]);
      acc[s][0] = __builtin_amdgcn_mfma_f32_16x16x32_bf16(a[0],  b0, acc[s][0], 0, 0, 0);
      acc[s][0] = __builtin_amdgcn_mfma_f32_16x16x32_bf16(a[1],  b1, acc[s][0], 0, 0, 0);
      acc[s][1] = __builtin_amdgcn_mfma_f32_16x16x32_bf16(a[3],  b0, acc[s][1], 0, 0, 0);
      acc[s][1] = __builtin_amdgcn_mfma_f32_16x16x32_bf16(a[4],  b1, acc[s][1], 0, 0, 0);
      acc[s][1] = __builtin_amdgcn_mfma_f32_16x16x32_bf16(a[5],  b2, acc[s][1], 0, 0, 0);
      acc[s][2] = __builtin_amdgcn_mfma_f32_16x16x32_bf16(a[6],  b0, acc[s][2], 0, 0, 0);
      acc[s][2] = __builtin_amdgcn_mfma_f32_16x16x32_bf16(a[7],  b1, acc[s][2], 0, 0, 0);
      acc[s][2] = __builtin_amdgcn_mfma_f32_16x16x32_bf16(a[8],  b2, acc[s][2], 0, 0, 0);
      acc[s][3] = __builtin_amdgcn_mfma_f32_16x16x32_bf16(a[10], b1, acc[s][3], 0, 0, 0);
      acc[s][3] = __builtin_amdgcn_mfma_f32_16x16x32_bf16(a[11], b2, acc[s][3], 0, 0, 0);
    }
  }

  float* op = outp + (((long)sk * 4 + b) * Cout + (co0 + w * 16 + g2 * 4)) * (long)Tout;
  #pragma unroll
  for (int r = 0; r < 4; ++r) {
    #pragma unroll
    for (int s = 0; s < 4; ++s) {
      float4 v4 = make_float4(acc[s][0][r], acc[s][1][r], acc[s][2][r], acc[s][3][r]);
      *(float4*)(op + (long)r * Tout + ((u0 + s * 16 + m) << 2)) = v4;
    }
  }
}

// ---------------- bn stats: sum split-K (write csum) + per-(c,b) partial stats ----------------
__global__ void bnsum_kernel(const float* __restrict__ p, float* __restrict__ sp,
                             float* __restrict__ csum, int C, int T, int SK) {
  int c = blockIdx.x, b = blockIdx.y;
  long stride = (long)4 * C * T;
  const float* r = p + ((long)b * C + c) * T;
  float* cw = csum + ((long)b * C + c) * T;
  float s = 0, q = 0;
  for (int t = threadIdx.x; t < T; t += 256) {
    float v = r[t];
    for (int k = 1; k < SK; ++k) v += r[t + k * stride];
    cw[t] = v;
    s += v; q += v * v;
  }
  #pragma unroll
  for (int off = 32; off; off >>= 1) { s += __shfl_down(s, off); q += __shfl_down(q, off); }
  __shared__ float rs[4], rq[4];
  int wid = threadIdx.x >> 6, lane = threadIdx.x & 63;
  if (lane == 0) { rs[wid] = s; rq[wid] = q; }
  __syncthreads();
  if (threadIdx.x == 0) {
    sp[c * 4 + b] = rs[0] + rs[1] + rs[2] + rs[3];
    sp[C * 4 + c * 4 + b] = rq[0] + rq[1] + rq[2] + rq[3];
  }
}

// ---------------- final conv: phase-decomposed 3-tap, FUSED bn-apply staging ----------------
__global__ __launch_bounds__(256)
void conv5_kernel(const float* __restrict__ csum_in, const float* __restrict__ sp,
                  const float* __restrict__ g, const float* __restrict__ be,
                  const float* __restrict__ wgt, const float* __restrict__ bias,
                  float* __restrict__ out, int Tout) {
  __shared__ unsigned short sv[64 * 66];
  __shared__ float wph[64 * 13];
  __shared__ float ssc[64], ssh[64];

  const int b = blockIdx.y;
  const int u0 = blockIdx.x * 64;
  const int Tin = Tout >> 2;
  const int tid = threadIdx.x;

  {
    int ci = tid >> 2, pp = tid & 3;
    float s0 = 0, s1 = 0, s2 = 0;
    #pragma unroll
    for (int k = 0; k < 7; ++k) {
      int d = (pp - 3 + k + 4) >> 2;
      float wv = wgt[ci * 7 + k];
      if (d == 0) s0 += wv; else if (d == 1) s1 += wv; else s2 += wv;
    }
    wph[ci * 13 + pp * 3 + 0] = s0;
    wph[ci * 13 + pp * 3 + 1] = s1;
    wph[ci * 13 + pp * 3 + 2] = s2;
  }
  if (tid < 64) {
    float S = sp[tid * 4] + sp[tid * 4 + 1] + sp[tid * 4 + 2] + sp[tid * 4 + 3];
    float Q = sp[256 + tid * 4] + sp[256 + tid * 4 + 1] + sp[256 + tid * 4 + 2] + sp[256 + tid * 4 + 3];
    float n = 4.f * (float)Tin;
    float mean = S / n;
    float var = Q / n - mean * mean;
    float sc = g[tid] * rsqrtf(var + 1e-5f);
    ssc[tid] = sc;
    ssh[tid] = be[tid] - mean * sc;
  }
  __syncthreads();

  const float* inb = csum_in + (long)b * 64 * Tin;
  for (int i = tid; i < 64 * 66; i += 256) {
    int ci = i / 66, uu = i - ci * 66;
    int u = u0 - 1 + uu;
    unsigned short v = 0;
    if (u >= 0 && u < Tin) {
      float t = inb[(long)ci * Tin + u];
      v = f2bf(leaky(t * ssc[ci] + ssh[ci]));
    }
    sv[ci * 66 + uu] = v;
  }
  __syncthreads();

  const int ul = tid >> 2;
  const int chunk = tid & 3;
  float a0 = 0, a1 = 0, a2 = 0, a3 = 0;
  #pragma unroll
  for (int cc = 0; cc < 16; ++cc) {
    int ci = chunk * 16 + cc;
    float v0 = bf2f(sv[ci * 66 + ul]);
    float v1 = bf2f(sv[ci * 66 + ul + 1]);
    float v2 = bf2f(sv[ci * 66 + ul + 2]);
    const float* wp = wph + ci * 13;
    a0 += v0 * wp[0] + v1 * wp[1];
    a1 += v0 * wp[3] + v1 * wp[4] + v2 * wp[5];
    a2 += v0 * wp[6] + v1 * wp[7] + v2 * wp[8];
    a3 += v1 * wp[10] + v2 * wp[11];
  }
  #pragma unroll
  for (int msk = 1; msk <= 2; msk <<= 1) {
    a0 += __shfl_xor(a0, msk);
    a1 += __shfl_xor(a1, msk);
    a2 += __shfl_xor(a2, msk);
    a3 += __shfl_xor(a3, msk);
  }
  if (chunk == 0) {
    float bv = bias[0];
    float4 r = make_float4(a0 + bv, a1 + bv, a2 + bv, a3 + bv);
    *(float4*)(out + (long)b * Tout + (long)(u0 + ul) * 4) = r;
  }
}

extern "C" void kernel_launch(void* const* d_in, const int* in_sizes, int n_in,
                              void* d_out, int out_size, void* d_ws, size_t ws_size,
                              hipStream_t stream) {
  const float* x     = (const float*)d_in[0];
  // d_in[1] = atoms: dead (sparse_code result unused by outputs)
  const float* ew    = (const float*)d_in[2];
  const float* eb    = (const float*)d_in[3];
  const float* w1    = (const float*)d_in[4];
  const float* b1    = (const float*)d_in[5];
  const float* g1    = (const float*)d_in[6];
  const float* be1   = (const float*)d_in[7];
  const float* w2    = (const float*)d_in[8];
  const float* b2    = (const float*)d_in[9];
  const float* g2    = (const float*)d_in[10];
  const float* be2   = (const float*)d_in[11];
  const float* w3    = (const float*)d_in[12];
  const float* b3    = (const float*)d_in[13];
  const float* up_w1 = (const float*)d_in[14];
  const float* up_b1 = (const float*)d_in[15];
  const float* bn_g1 = (const float*)d_in[16];
  const float* bn_b1 = (const float*)d_in[17];
  const float* up_w2 = (const float*)d_in[18];
  const float* up_b2 = (const float*)d_in[19];
  const float* bn_g2 = (const float*)d_in[20];
  const float* bn_b2 = (const float*)d_in[21];
  const float* up_w3 = (const float*)d_in[22];
  const float* up_b3 = (const float*)d_in[23];
  const float* bn_g3 = (const float*)d_in[24];
  const float* bn_b3 = (const float*)d_in[25];
  const float* up_w4 = (const float*)d_in[26];
  const float* up_b4 = (const float*)d_in[27];
  const float* bn_g4 = (const float*)d_in[28];
  const float* bn_b4 = (const float*)d_in[29];
  const float* up_w5 = (const float*)d_in[30];
  const float* up_b5 = (const float*)d_in[31];

  float* out = (float*)d_out;              // [0,131072) = y, [131072,135168) = ctx_out

  float* ws = (float*)d_ws;
  float* ctxb   = ws;                      // 4096
  float* gpart  = ctxb + 4096;             // 32768
  float* t2     = gpart + 32768;           // 4096
  float* statsp = t2 + 4096;               // 4096
  float* csum   = statsp + 4096;           // 2097152
  float* pbuf   = csum + 2097152;          // 4194304
  unsigned short* encbf = (unsigned short*)(pbuf + 4194304);  // 524288 u16
  unsigned short* wbuf  = encbf + 524288;  // 5734400 u16

  // weight packing + embed (deep-pipelined LDS staging) + fused ctx
  pack_all<<<2720, 256, 0, stream>>>(up_w1, up_w2, up_w3, up_w4, wbuf);
  embed_mfma<<<512, 256, 0, stream>>>(x, ew, eb, encbf, ctxb);

  // ctx MLP (split-K gemms, deterministic partial sums)
  gemm_p<<<dim3(32, 8), 256, 0, stream>>>(ctxb, w1, gpart);
  lnsum_kernel<<<4, 256, 0, stream>>>(gpart, b1, g1, be1, t2);
  gemm_p<<<dim3(32, 8), 256, 0, stream>>>(t2, w2, gpart);
  lnsum_kernel<<<4, 256, 0, stream>>>(gpart, b2, g2, be2, t2);
  gemm_p<<<dim3(32, 8), 256, 0, stream>>>(t2, w3, gpart);
  fin_kernel<<<16, 256, 0, stream>>>(gpart, b3, out + 131072);

  // ---- stage 1: (4,1024,128) -> (4,512,128), UPS=1, SK=8 ----
  conv_mfma<1, 8><<<512, 256, 22400, stream>>>(encbf, wbuf, pbuf, 1024, 512, 128);
  bnsum_kernel<<<dim3(512, 4), 256, 0, stream>>>(pbuf, statsp, csum, 512, 128, 8);

  // ---- stage 2: (4,512,128) -bn+ph-> (4,256,512), SK=8 ----
  conv_ph<8><<<256, 256, 10560, stream>>>(csum, statsp, bn_g1, bn_b1, wbuf + 3670016, pbuf, 512, 256, 128);
  bnsum_kernel<<<dim3(256, 4), 256, 0, stream>>>(pbuf, statsp, csum, 256, 512, 8);

  // ---- stage 3: (4,256,512) -bn+ph-> (4,128,2048), SK=4 ----
  conv_ph<4><<<256, 256, 10560, stream>>>(csum, statsp, bn_g2, bn_b2, wbuf + 5242880, pbuf, 256, 128, 512);
  bnsum_kernel<<<dim3(128, 4), 256, 0, stream>>>(pbuf, statsp, csum, 128, 2048, 4);

  // ---- stage 4: (4,128,2048) -bn+ph-> (4,64,8192), SK=2 ----
  conv_ph<2><<<256, 256, 10560, stream>>>(csum, statsp, bn_g3, bn_b3, wbuf + 5636096, pbuf, 128, 64, 2048);
  bnsum_kernel<<<dim3(64, 4), 256, 0, stream>>>(pbuf, statsp, csum, 64, 8192, 2);

  // ---- stage 5: (4,64,8192) -bn+ph-> (4,1,32768) ----
  conv5_kernel<<<dim3(128, 4), 256, 0, stream>>>(csum, statsp, bn_g4, bn_b4, up_w5, up_b5, out, 32768);
}